// Round 1
// baseline (118824.512 us; speedup 1.0000x reference)
//
#include <hip/hip_runtime.h>
#include <math.h>

// GRU seq2seq (Informer-style RNN) on MI355X.
// Round 1: fp32 persistent kernel, 256 blocks x 512 threads (1 block/CU,
// co-resident => hand-rolled grid barrier is safe), 2 barriers per time step.
// Autoregressive feedback folded into a precomputed Wf = W_ih0_dec[:, :7] @ out_W
// so the decoder loop never materializes pred; predictions come from an
// epilogue GEMM over stored h1 history.
//
// Workspace budget (floats):
//   cnt(64) | h0[2][65536] | h1[2][65536] | bf0[3072] | Wf[3072*1024] | hist[168][65536]
//   = 14,421,056 floats = 57.7 MB.

#define B64   64
#define DM    1024
#define TENC  192
#define TDEC  216
#define LBL   48
#define NPRED 168
#define NBLK  256
#define NTHR  512
#define HS    (DM * B64)   // one hidden-state buffer, floats

#define OFS_H0   64
#define OFS_H1   (OFS_H0 + 2 * HS)
#define OFS_BF0  (OFS_H1 + 2 * HS)
#define OFS_WF   (OFS_BF0 + 3072)
#define OFS_HIST (OFS_WF + 3072 * DM)

__device__ __forceinline__ float sigm(float x) { return 1.0f / (1.0f + __expf(-x)); }

// Hierarchical grid barrier: 8 counters, 32 blocks each (bx & 7).
// Monotone counters (never reset); target = epoch * 32.
__device__ __forceinline__ void gridbar(unsigned* cnt, int tid, int bx, unsigned target32) {
  __syncthreads();
  if (tid == 0) {
    __threadfence();  // release: make our h-writes visible before arrival
    __hip_atomic_fetch_add(&cnt[bx & 7], 1u, __ATOMIC_RELEASE, __HIP_MEMORY_SCOPE_AGENT);
  }
  if (tid < 8) {
    while (__hip_atomic_load(&cnt[tid], __ATOMIC_RELAXED, __HIP_MEMORY_SCOPE_AGENT) < target32)
      __builtin_amdgcn_s_sleep(2);
  }
  __syncthreads();
  __threadfence();  // acquire: invalidate stale cached h before reading
}

// Packed hidden layout: element (k, b) lives at ((k>>2)<<8) + (b<<2) + (k&3),
// i.e. [k/4][b][4] -> lane b loads a float4 of 4 consecutive k (coalesced 1KB/wave).

// Phase A: layer-0 GRU cell for 4 units/block. 512 threads = 64 b x 4 units x 2 k-halves.
__device__ __forceinline__ void phaseA(
    bool autoreg, int t, int seqT,
    const float* __restrict__ xin, const float* __restrict__ xmk,
    const float* __restrict__ Wih0, const float* __restrict__ Whh0,
    const float* __restrict__ bih0, const float* __restrict__ bhh0,
    const float* __restrict__ bf0, const float* __restrict__ Wf,
    const float* __restrict__ h0r, float* __restrict__ h0w,
    const float* __restrict__ h1r,
    int b, int kh, int u, float4* red, int tid)
{
  const int jr = u, jz = DM + u, jn = 2 * DM + u;
  float ar = 0.f, az = 0.f, ain = 0.f, ahn = 0.f;
  if (kh == 0) {
    if (autoreg) {
      // fused bias bf0 = b_ih0 + W_ih0[:, :7] @ out_b ; marks still explicit
      ar = bf0[jr] + bhh0[jr];
      az = bf0[jz] + bhh0[jz];
      ain = bf0[jn];
      ahn = bhh0[jn];
      const float* mr = xmk + (b * seqT + t) * 4;
#pragma unroll
      for (int m = 0; m < 4; ++m) {
        float xv = mr[m];
        ar = fmaf(Wih0[jr * 11 + 7 + m], xv, ar);
        az = fmaf(Wih0[jz * 11 + 7 + m], xv, az);
        ain = fmaf(Wih0[jn * 11 + 7 + m], xv, ain);
      }
    } else {
      ar = bih0[jr] + bhh0[jr];
      az = bih0[jz] + bhh0[jz];
      ain = bih0[jn];
      ahn = bhh0[jn];
      const float* xr7 = xin + (b * seqT + t) * 7;
      const float* mr  = xmk + (b * seqT + t) * 4;
#pragma unroll
      for (int c = 0; c < 7; ++c) {
        float xv = xr7[c];
        ar = fmaf(Wih0[jr * 11 + c], xv, ar);
        az = fmaf(Wih0[jz * 11 + c], xv, az);
        ain = fmaf(Wih0[jn * 11 + c], xv, ain);
      }
#pragma unroll
      for (int m = 0; m < 4; ++m) {
        float xv = mr[m];
        ar = fmaf(Wih0[jr * 11 + 7 + m], xv, ar);
        az = fmaf(Wih0[jz * 11 + 7 + m], xv, az);
        ain = fmaf(Wih0[jn * 11 + 7 + m], xv, ain);
      }
    }
  }
  const float* wr = Whh0 + jr * DM;
  const float* wz = Whh0 + jz * DM;
  const float* wn = Whh0 + jn * DM;
  const float4* hv = (const float4*)h0r;
  const int k4b = kh << 7;
  if (autoreg) {
    const float* fr = Wf + jr * DM;
    const float* fz = Wf + jz * DM;
    const float* fn = Wf + jn * DM;
    const float4* gv = (const float4*)h1r;
#pragma unroll 2
    for (int k4 = k4b; k4 < k4b + 128; ++k4) {
      const int k = k4 << 2;
      float4 h = hv[(k4 << 6) + b];
      float4 g = gv[(k4 << 6) + b];
      ar = fmaf(wr[k], h.x, ar);     az = fmaf(wz[k], h.x, az);     ahn = fmaf(wn[k], h.x, ahn);
      ar = fmaf(fr[k], g.x, ar);     az = fmaf(fz[k], g.x, az);     ain = fmaf(fn[k], g.x, ain);
      ar = fmaf(wr[k + 1], h.y, ar); az = fmaf(wz[k + 1], h.y, az); ahn = fmaf(wn[k + 1], h.y, ahn);
      ar = fmaf(fr[k + 1], g.y, ar); az = fmaf(fz[k + 1], g.y, az); ain = fmaf(fn[k + 1], g.y, ain);
      ar = fmaf(wr[k + 2], h.z, ar); az = fmaf(wz[k + 2], h.z, az); ahn = fmaf(wn[k + 2], h.z, ahn);
      ar = fmaf(fr[k + 2], g.z, ar); az = fmaf(fz[k + 2], g.z, az); ain = fmaf(fn[k + 2], g.z, ain);
      ar = fmaf(wr[k + 3], h.w, ar); az = fmaf(wz[k + 3], h.w, az); ahn = fmaf(wn[k + 3], h.w, ahn);
      ar = fmaf(fr[k + 3], g.w, ar); az = fmaf(fz[k + 3], g.w, az); ain = fmaf(fn[k + 3], g.w, ain);
    }
  } else {
#pragma unroll 4
    for (int k4 = k4b; k4 < k4b + 128; ++k4) {
      const int k = k4 << 2;
      float4 h = hv[(k4 << 6) + b];
      ar = fmaf(wr[k], h.x, ar);     az = fmaf(wz[k], h.x, az);     ahn = fmaf(wn[k], h.x, ahn);
      ar = fmaf(wr[k + 1], h.y, ar); az = fmaf(wz[k + 1], h.y, az); ahn = fmaf(wn[k + 1], h.y, ahn);
      ar = fmaf(wr[k + 2], h.z, ar); az = fmaf(wz[k + 2], h.z, az); ahn = fmaf(wn[k + 2], h.z, ahn);
      ar = fmaf(wr[k + 3], h.w, ar); az = fmaf(wz[k + 3], h.w, az); ahn = fmaf(wn[k + 3], h.w, ahn);
    }
  }
  if (kh) red[tid & 255] = make_float4(ar, az, ain, ahn);
  __syncthreads();
  if (!kh) {
    float4 o = red[tid];
    ar += o.x; az += o.y; ain += o.z; ahn += o.w;
    float rg = sigm(ar), zg = sigm(az);
    float ng = tanhf(fmaf(rg, ahn, ain));
    const int hidx = ((u >> 2) << 8) + (b << 2) + (u & 3);
    float hp = h0r[hidx];
    h0w[hidx] = fmaf(zg, hp - ng, ng);  // (1-z)*n + z*h
  }
}

// Phase B: layer-1 GRU cell. x-side from h0_new, h-side from h1.
__device__ __forceinline__ void phaseB(
    const float* __restrict__ Wih1, const float* __restrict__ Whh1,
    const float* __restrict__ bih1, const float* __restrict__ bhh1,
    const float* __restrict__ xr, const float* __restrict__ h1r,
    float* __restrict__ h1w, float* __restrict__ hist,
    int b, int kh, int u, float4* red, int tid)
{
  const int jr = u, jz = DM + u, jn = 2 * DM + u;
  float ar = 0.f, az = 0.f, ain = 0.f, ahn = 0.f;
  if (!kh) {
    ar = bih1[jr] + bhh1[jr];
    az = bih1[jz] + bhh1[jz];
    ain = bih1[jn];
    ahn = bhh1[jn];
  }
  const float* ir_ = Wih1 + jr * DM;
  const float* iz_ = Wih1 + jz * DM;
  const float* in_ = Wih1 + jn * DM;
  const float* hr_ = Whh1 + jr * DM;
  const float* hz_ = Whh1 + jz * DM;
  const float* hn_ = Whh1 + jn * DM;
  const float4* xv4 = (const float4*)xr;
  const float4* hv4 = (const float4*)h1r;
  const int k4b = kh << 7;
#pragma unroll 2
  for (int k4 = k4b; k4 < k4b + 128; ++k4) {
    const int k = k4 << 2;
    float4 x = xv4[(k4 << 6) + b];
    float4 h = hv4[(k4 << 6) + b];
    ar = fmaf(ir_[k], x.x, ar);     az = fmaf(iz_[k], x.x, az);     ain = fmaf(in_[k], x.x, ain);
    ar = fmaf(hr_[k], h.x, ar);     az = fmaf(hz_[k], h.x, az);     ahn = fmaf(hn_[k], h.x, ahn);
    ar = fmaf(ir_[k + 1], x.y, ar); az = fmaf(iz_[k + 1], x.y, az); ain = fmaf(in_[k + 1], x.y, ain);
    ar = fmaf(hr_[k + 1], h.y, ar); az = fmaf(hz_[k + 1], h.y, az); ahn = fmaf(hn_[k + 1], h.y, ahn);
    ar = fmaf(ir_[k + 2], x.z, ar); az = fmaf(iz_[k + 2], x.z, az); ain = fmaf(in_[k + 2], x.z, ain);
    ar = fmaf(hr_[k + 2], h.z, ar); az = fmaf(hz_[k + 2], h.z, az); ahn = fmaf(hn_[k + 2], h.z, ahn);
    ar = fmaf(ir_[k + 3], x.w, ar); az = fmaf(iz_[k + 3], x.w, az); ain = fmaf(in_[k + 3], x.w, ain);
    ar = fmaf(hr_[k + 3], h.w, ar); az = fmaf(hz_[k + 3], h.w, az); ahn = fmaf(hn_[k + 3], h.w, ahn);
  }
  if (kh) red[tid & 255] = make_float4(ar, az, ain, ahn);
  __syncthreads();
  if (!kh) {
    float4 o = red[tid];
    ar += o.x; az += o.y; ain += o.z; ahn += o.w;
    float rg = sigm(ar), zg = sigm(az);
    float ng = tanhf(fmaf(rg, ahn, ain));
    const int hidx = ((u >> 2) << 8) + (b << 2) + (u & 3);
    float hp = h1r[hidx];
    float hnew = fmaf(zg, hp - ng, ng);
    h1w[hidx] = hnew;
    if (hist) hist[hidx] = hnew;
  }
}

// Prologue: Wf = W_ih0_dec[:, :7] @ out_W  (3072 x 1024), bf0 = b_ih0_dec + W_ih0_dec[:, :7] @ out_b
__global__ __launch_bounds__(256) void prep_kernel(
    const float* __restrict__ dWih0, const float* __restrict__ dbih0,
    const float* __restrict__ outW, const float* __restrict__ outb,
    float* __restrict__ ws)
{
  const int bx = blockIdx.x;
  const int j = bx >> 2;
  const int k = ((bx & 3) << 8) + threadIdx.x;
  float acc = 0.f;
#pragma unroll
  for (int c = 0; c < 7; ++c) acc = fmaf(dWih0[j * 11 + c], outW[c * DM + k], acc);
  ws[OFS_WF + j * DM + k] = acc;
  if ((bx & 3) == 0 && threadIdx.x == 0) {
    float bb = dbih0[j];
#pragma unroll
    for (int c = 0; c < 7; ++c) bb = fmaf(dWih0[j * 11 + c], outb[c], bb);
    ws[OFS_BF0 + j] = bb;
  }
}

__global__ __launch_bounds__(NTHR) void gru_persist(
    const float* __restrict__ xe,  const float* __restrict__ xme,
    const float* __restrict__ xd,  const float* __restrict__ xmd,
    const float* __restrict__ eWih0, const float* __restrict__ eWhh0,
    const float* __restrict__ ebih0, const float* __restrict__ ebhh0,
    const float* __restrict__ eWih1, const float* __restrict__ eWhh1,
    const float* __restrict__ ebih1, const float* __restrict__ ebhh1,
    const float* __restrict__ dWih0, const float* __restrict__ dWhh0,
    const float* __restrict__ dbih0, const float* __restrict__ dbhh0,
    const float* __restrict__ dWih1, const float* __restrict__ dWhh1,
    const float* __restrict__ dbih1, const float* __restrict__ dbhh1,
    float* __restrict__ ws)
{
  const int tid = threadIdx.x;
  const int bx = blockIdx.x;
  const int b = tid & 63;
  const int kh = __builtin_amdgcn_readfirstlane(tid >> 8);         // wave-uniform
  const int ui = __builtin_amdgcn_readfirstlane((tid >> 6) & 3);   // wave-uniform
  const int u = (bx << 2) + ui;

  unsigned* cnt = (unsigned*)ws;
  float* h0 = ws + OFS_H0;
  float* h1 = ws + OFS_H1;
  const float* bf0 = ws + OFS_BF0;
  const float* Wf = ws + OFS_WF;
  float* hist = ws + OFS_HIST;

  __shared__ float4 red[256];
  unsigned epoch = 0;

  for (int t = 0; t < TENC; ++t) {
    const int r = t & 1, w = r ^ 1;
    phaseA(false, t, TENC, xe, xme, eWih0, eWhh0, ebih0, ebhh0, nullptr, nullptr,
           h0 + r * HS, h0 + w * HS, nullptr, b, kh, u, red, tid);
    gridbar(cnt, tid, bx, (++epoch) * 32u);
    phaseB(eWih1, eWhh1, ebih1, ebhh1, h0 + w * HS, h1 + r * HS, h1 + w * HS, nullptr,
           b, kh, u, red, tid);
    gridbar(cnt, tid, bx, (++epoch) * 32u);
  }
  for (int t = 0; t < TDEC; ++t) {
    const int r = t & 1, w = r ^ 1;   // (192+t)&1 == t&1, so parity continues seamlessly
    phaseA(t >= LBL, t, TDEC, xd, xmd, dWih0, dWhh0, dbih0, dbhh0, bf0, Wf,
           h0 + r * HS, h0 + w * HS, h1 + r * HS, b, kh, u, red, tid);
    gridbar(cnt, tid, bx, (++epoch) * 32u);
    phaseB(dWih1, dWhh1, dbih1, dbhh1, h0 + w * HS, h1 + r * HS, h1 + w * HS,
           (t >= LBL) ? (hist + (t - LBL) * HS) : nullptr, b, kh, u, red, tid);
    gridbar(cnt, tid, bx, (++epoch) * 32u);
  }
}

// Epilogue: preds[b, ti, c] = h1_hist[ti] . out_W[c] + out_b[c]
__global__ __launch_bounds__(64) void proj_kernel(
    const float* __restrict__ ws, const float* __restrict__ outW,
    const float* __restrict__ outb, float* __restrict__ out)
{
  const int bx = blockIdx.x;
  const int ti = bx / 7;
  const int c = bx % 7;
  const int b = threadIdx.x;
  const float4* hv = (const float4*)(ws + OFS_HIST + (size_t)ti * HS);
  const float* wrow = outW + c * DM;
  float acc = outb[c];
#pragma unroll 4
  for (int k4 = 0; k4 < 256; ++k4) {
    const int k = k4 << 2;
    float4 h = hv[(k4 << 6) + b];
    acc = fmaf(h.x, wrow[k], acc);
    acc = fmaf(h.y, wrow[k + 1], acc);
    acc = fmaf(h.z, wrow[k + 2], acc);
    acc = fmaf(h.w, wrow[k + 3], acc);
  }
  out[b * (NPRED * 7) + ti * 7 + c] = acc;
}

extern "C" void kernel_launch(void* const* d_in, const int* in_sizes, int n_in,
                              void* d_out, int out_size, void* d_ws, size_t ws_size,
                              hipStream_t stream) {
  (void)in_sizes; (void)n_in; (void)out_size; (void)ws_size;
  const float* xe    = (const float*)d_in[0];
  const float* xme   = (const float*)d_in[1];
  const float* xd    = (const float*)d_in[2];
  const float* xmd   = (const float*)d_in[3];
  const float* eWih0 = (const float*)d_in[4];
  const float* eWhh0 = (const float*)d_in[5];
  const float* ebih0 = (const float*)d_in[6];
  const float* ebhh0 = (const float*)d_in[7];
  const float* eWih1 = (const float*)d_in[8];
  const float* eWhh1 = (const float*)d_in[9];
  const float* ebih1 = (const float*)d_in[10];
  const float* ebhh1 = (const float*)d_in[11];
  const float* dWih0 = (const float*)d_in[12];
  const float* dWhh0 = (const float*)d_in[13];
  const float* dbih0 = (const float*)d_in[14];
  const float* dbhh0 = (const float*)d_in[15];
  const float* dWih1 = (const float*)d_in[16];
  const float* dWhh1 = (const float*)d_in[17];
  const float* dbih1 = (const float*)d_in[18];
  const float* dbhh1 = (const float*)d_in[19];
  const float* outW  = (const float*)d_in[20];
  const float* outb  = (const float*)d_in[21];
  float* ws = (float*)d_ws;

  // zero barrier counters + both h ping-pong buffer pairs (ws is poisoned 0xAA)
  hipMemsetAsync(d_ws, 0, (size_t)(OFS_BF0) * sizeof(float), stream);
  prep_kernel<<<12288, 256, 0, stream>>>(dWih0, dbih0, outW, outb, ws);
  gru_persist<<<NBLK, NTHR, 0, stream>>>(xe, xme, xd, xmd,
                                         eWih0, eWhh0, ebih0, ebhh0,
                                         eWih1, eWhh1, ebih1, ebhh1,
                                         dWih0, dWhh0, dbih0, dbhh0,
                                         dWih1, dWhh1, dbih1, dbhh1, ws);
  proj_kernel<<<NPRED * 7, 64, 0, stream>>>(ws, outW, outb, (float*)d_out);
}

// Round 2
// 39845.624 us; speedup vs baseline: 2.9821x; 2.9821x over previous
//
#include <hip/hip_runtime.h>
#include <math.h>

// GRU seq2seq on MI355X — Round 2: LDS-stationary f16 weights + MFMA.
// 256 blocks x 512 threads (1 block/CU, co-resident grid barrier).
// Each CU owns 4 hidden units (48 weight rows packed as three/four 16-row
// MFMA tiles in LDS, f16, fragment order). Per step: 2 phases, 2 barriers.
// h broadcast via packed-f16 global buffers; h_prev kept in registers.
// Autoregression folded via Wf = dW_ih0[:, :7] @ out_W (prep kernel).

typedef _Float16 half8 __attribute__((ext_vector_type(8)));
typedef _Float16 half4f __attribute__((ext_vector_type(4)));
typedef float f32x4 __attribute__((ext_vector_type(4)));

#define DM    1024
#define TENC  192
#define TDEC  216
#define LBL   48
#define NPRED 168
#define HB    131072            // one packed h buffer: 1024*64*2 bytes
#define HE    65536             // elements per h buffer

// workspace byte offsets
#define OFF_H0P0 1024
#define OFF_EH10 (OFF_H0P0 + 2*HB)
#define OFF_DH1  (OFF_EH10 + 2*HB)
#define OFF_WF   (OFF_DH1 + 217*HB)
#define OFF_BF0  (OFF_WF + 3072*1024*2)

// LDS byte offsets (dynamic shared, 140032 B total)
#define L_TA0 0
#define L_TA1 32768
#define L_TB0 65536
#define L_TB1 98304
#define L_XW  131072            // xw[3][4][12] f32 = 576 B
#define L_BA  131648            // 16 f32
#define L_BAA 131712            // 16 f32
#define L_BB  131776            // 16 f32
#define L_TR  131840            // 8 waves * 256 f32 = 8192 B
#define SMEM_BYTES (131840 + 8192)

__device__ __forceinline__ float sigm(float x) { return 1.0f / (1.0f + __expf(-x)); }

// ---- grid barrier (unchanged from round 1 — verified correct) ----
__device__ __forceinline__ void gridbar(unsigned* cnt, int tid, int bx, unsigned target32) {
  __syncthreads();
  if (tid == 0) {
    __threadfence();
    __hip_atomic_fetch_add(&cnt[bx & 7], 1u, __ATOMIC_RELEASE, __HIP_MEMORY_SCOPE_AGENT);
  }
  if (tid < 8) {
    while (__hip_atomic_load(&cnt[tid], __ATOMIC_RELAXED, __HIP_MEMORY_SCOPE_AGENT) < target32)
      __builtin_amdgcn_s_sleep(2);
  }
  __syncthreads();
  __threadfence();
}

// ---- LDS tile fill: pack 16 rows (row map per 4-row gate group, -1 = zeros)
// into MFMA A-fragment order: elem((kb,quad,m),j) = ((kb*64 + quad*16 + m)*8 + j)
__device__ __forceinline__ void fill_tile_f32(char* smem, int off, const float* __restrict__ src,
                                              int u0, int g0, int g1, int g2, int g3, int tid) {
  const int w = tid >> 6, lane = tid & 63;
  int gsel[4] = {g0, g1, g2, g3};
#pragma unroll
  for (int mm = 0; mm < 2; ++mm) {
    const int m = w + mm * 8;
    const int g = gsel[m >> 2];
    const long srow = (g < 0) ? -1 : (long)g * DM + u0 + (m & 3);
#pragma unroll
    for (int p = 0; p < 4; ++p) {
      const int k = p * 256 + lane * 4;
      half4f hv;
      if (srow >= 0) {
        float4 v = *(const float4*)(src + srow * DM + k);
        hv = (half4f){(_Float16)v.x, (_Float16)v.y, (_Float16)v.z, (_Float16)v.w};
      } else {
        hv = (half4f){(_Float16)0.f, (_Float16)0.f, (_Float16)0.f, (_Float16)0.f};
      }
      const int kb = k >> 5, q = (k >> 3) & 3;
      const int elem = (kb * 64 + q * 16 + m) * 8 + (k & 7);
      *(half4f*)(smem + off + elem * 2) = hv;
    }
  }
}

__device__ __forceinline__ void fill_tile_f16(char* smem, int off, const _Float16* __restrict__ src,
                                              int u0, int g0, int g1, int g2, int g3, int tid) {
  const int w = tid >> 6, lane = tid & 63;
  int gsel[4] = {g0, g1, g2, g3};
#pragma unroll
  for (int mm = 0; mm < 2; ++mm) {
    const int m = w + mm * 8;
    const int g = gsel[m >> 2];
    const long srow = (g < 0) ? -1 : (long)g * DM + u0 + (m & 3);
#pragma unroll
    for (int p = 0; p < 4; ++p) {
      const int k = p * 256 + lane * 4;
      half4f hv;
      if (srow >= 0) hv = *(const half4f*)(src + srow * DM + k);
      else hv = (half4f){(_Float16)0.f, (_Float16)0.f, (_Float16)0.f, (_Float16)0.f};
      const int kb = k >> 5, q = (k >> 3) & 3;
      const int elem = (kb * 64 + q * 16 + m) * 8 + (k & 7);
      *(half4f*)(smem + off + elem * 2) = hv;
    }
  }
}

// small per-CU constants: x-side weight slice + fused biases
__device__ __forceinline__ void fill_small(char* smem, int u0, int tid,
    const float* __restrict__ Wih0, const float* __restrict__ bihA, const float* __restrict__ bhhA,
    const float* __restrict__ bih1, const float* __restrict__ bhh1, const float* __restrict__ bf0) {
  if (tid < 132) {
    const int rr = tid / 11, c = tid - rr * 11;
    const int g = rr >> 2, ul = rr & 3;
    ((float*)(smem + L_XW))[(g * 4 + ul) * 12 + c] = Wih0[(g * DM + u0 + ul) * 11 + c];
  }
  if (tid < 4) {
    const int u = u0 + tid;
    float* bA = (float*)(smem + L_BA);
    bA[tid] = bihA[u] + bhhA[u];
    bA[4 + tid] = bihA[DM + u] + bhhA[DM + u];
    bA[8 + tid] = bhhA[2 * DM + u];
    bA[12 + tid] = bihA[2 * DM + u];
    float* bB = (float*)(smem + L_BB);
    bB[tid] = bih1[u] + bhh1[u];
    bB[4 + tid] = bih1[DM + u] + bhh1[DM + u];
    bB[8 + tid] = bhh1[2 * DM + u];
    bB[12 + tid] = bih1[2 * DM + u];
    if (bf0) {
      float* bAa = (float*)(smem + L_BAA);
      bAa[tid] = bf0[u] + bhhA[u];
      bAa[4 + tid] = bf0[DM + u] + bhhA[DM + u];
      bAa[8 + tid] = bhhA[2 * DM + u];
      bAa[12 + tid] = bf0[2 * DM + u];
    }
  }
}

// ---- K-loop GEMMs. Wave covers batch group bs..bs+15 and K-slice kb0..kb0+15.
__device__ __forceinline__ f32x4 gemm1(const char* smem, int toff, const _Float16* __restrict__ bsrc,
                                       int kb0, int lane, int bs) {
  const half8* T = (const half8*)(smem + toff);
  const half8* Bp = (const half8*)bsrc + ((lane >> 4) << 6) + bs + (lane & 15);
  f32x4 a0 = (f32x4){0.f, 0.f, 0.f, 0.f}, a1 = a0;
#pragma unroll 4
  for (int kb = kb0; kb < kb0 + 16; kb += 2) {
    half8 x0 = T[(kb << 6) + lane];
    half8 y0 = Bp[(size_t)kb << 8];
    half8 x1 = T[((kb + 1) << 6) + lane];
    half8 y1 = Bp[(size_t)(kb + 1) << 8];
    a0 = __builtin_amdgcn_mfma_f32_16x16x32_f16(x0, y0, a0, 0, 0, 0);
    a1 = __builtin_amdgcn_mfma_f32_16x16x32_f16(x1, y1, a1, 0, 0, 0);
  }
  return a0 + a1;
}

__device__ __forceinline__ f32x4 gemm2(const char* smem, int t0, int t1,
                                       const _Float16* __restrict__ s0, const _Float16* __restrict__ s1,
                                       int kb0, int lane, int bs) {
  const half8* T0 = (const half8*)(smem + t0);
  const half8* T1 = (const half8*)(smem + t1);
  const int bidx = ((lane >> 4) << 6) + bs + (lane & 15);
  const half8* B0 = (const half8*)s0 + bidx;
  const half8* B1 = (const half8*)s1 + bidx;
  f32x4 a0 = (f32x4){0.f, 0.f, 0.f, 0.f}, a1 = a0;
#pragma unroll 4
  for (int kb = kb0; kb < kb0 + 16; ++kb) {
    half8 x0 = T0[(kb << 6) + lane];
    half8 y0 = B0[(size_t)kb << 8];
    half8 x1 = T1[(kb << 6) + lane];
    half8 y1 = B1[(size_t)kb << 8];
    a0 = __builtin_amdgcn_mfma_f32_16x16x32_f16(x0, y0, a0, 0, 0, 0);
    a1 = __builtin_amdgcn_mfma_f32_16x16x32_f16(x1, y1, a1, 0, 0, 0);
  }
  return a0 + a1;
}

// ---- gate epilogue. acc rows: [r*4 | z*4 | nh*4 | ni*4] (unit = reg index).
// xmode: 0 = none (phase B), 1 = full 7+4 inputs, 2 = marks only (autoreg).
__device__ __forceinline__ void epilogue(f32x4 acc, char* smem, int tid, int biasOff,
                                         int xmode, const float* __restrict__ xin,
                                         const float* __restrict__ xmk, int t, int seqT,
                                         int u0, float& hprev, _Float16* __restrict__ dst) {
  const int lane = tid & 63, w = tid >> 6;
  float* tr = (float*)(smem + L_TR) + (w << 8);
  const int quad = lane >> 4, col = lane & 15;
  tr[(quad * 4 + 0) * 16 + col] = acc[0];
  tr[(quad * 4 + 1) * 16 + col] = acc[1];
  tr[(quad * 4 + 2) * 16 + col] = acc[2];
  tr[(quad * 4 + 3) * 16 + col] = acc[3];
  __syncthreads();
  if (w < 4) {
    const float* trA = (const float*)(smem + L_TR) + (w << 8);
    const float* trB = trA + (4 << 8);
    const int ul = quad;
    const int b = (w << 4) + col;
    const int u = u0 + ul;
    float vr  = trA[ul * 16 + col]        + trB[ul * 16 + col];
    float vz  = trA[(4 + ul) * 16 + col]  + trB[(4 + ul) * 16 + col];
    float vnh = trA[(8 + ul) * 16 + col]  + trB[(8 + ul) * 16 + col];
    float vni = trA[(12 + ul) * 16 + col] + trB[(12 + ul) * 16 + col];
    const float* bias = (const float*)(smem + biasOff);
    const float* xw = (const float*)(smem + L_XW);
    float xr = 0.f, xz = 0.f, xn = 0.f;
    if (xmode == 1) {
      const float* xp = xin + (size_t)(b * seqT + t) * 7;
      const float* mp = xmk + (size_t)(b * seqT + t) * 4;
#pragma unroll
      for (int c = 0; c < 7; ++c) {
        float v = xp[c];
        xr = fmaf(xw[ul * 12 + c], v, xr);
        xz = fmaf(xw[(4 + ul) * 12 + c], v, xz);
        xn = fmaf(xw[(8 + ul) * 12 + c], v, xn);
      }
#pragma unroll
      for (int m = 0; m < 4; ++m) {
        float v = mp[m];
        xr = fmaf(xw[ul * 12 + 7 + m], v, xr);
        xz = fmaf(xw[(4 + ul) * 12 + 7 + m], v, xz);
        xn = fmaf(xw[(8 + ul) * 12 + 7 + m], v, xn);
      }
    } else if (xmode == 2) {
      const float* mp = xmk + (size_t)(b * seqT + t) * 4;
#pragma unroll
      for (int m = 0; m < 4; ++m) {
        float v = mp[m];
        xr = fmaf(xw[ul * 12 + 7 + m], v, xr);
        xz = fmaf(xw[(4 + ul) * 12 + 7 + m], v, xz);
        xn = fmaf(xw[(8 + ul) * 12 + 7 + m], v, xn);
      }
    }
    const float rp = vr + bias[ul] + xr;
    const float zp = vz + bias[4 + ul] + xz;
    const float rg = sigm(rp), zg = sigm(zp);
    const float np = (vni + bias[12 + ul] + xn) + rg * (vnh + bias[8 + ul]);
    const float ng = tanhf(np);
    const float hn = ng + zg * (hprev - ng);
    hprev = hn;
    dst[((u >> 3) * 64 + b) * 8 + (u & 7)] = (_Float16)hn;
  }
}

// ---- prep: Wf = dW_ih0[:, :7] @ out_W (f16), bf0 = db_ih0 + dW_ih0[:, :7] @ out_b
__global__ __launch_bounds__(256) void prep_wf(const float* __restrict__ dWih0,
                                               const float* __restrict__ dbih0,
                                               const float* __restrict__ outW,
                                               const float* __restrict__ outb,
                                               char* __restrict__ ws) {
  const int j = blockIdx.x;
  _Float16* wf = (_Float16*)(ws + OFF_WF);
  float* bf0 = (float*)(ws + OFF_BF0);
  float wrow[7];
#pragma unroll
  for (int c = 0; c < 7; ++c) wrow[c] = dWih0[j * 11 + c];
#pragma unroll
  for (int p = 0; p < 4; ++p) {
    const int k = p * 256 + threadIdx.x;
    float acc = 0.f;
#pragma unroll
    for (int c = 0; c < 7; ++c) acc = fmaf(wrow[c], outW[c * DM + k], acc);
    wf[(size_t)j * DM + k] = (_Float16)acc;
  }
  if (threadIdx.x == 0) {
    float bb = dbih0[j];
#pragma unroll
    for (int c = 0; c < 7; ++c) bb = fmaf(wrow[c], outb[c], bb);
    bf0[j] = bb;
  }
}

__global__ __launch_bounds__(512) void gru_persist(
    const float* __restrict__ xe,  const float* __restrict__ xme,
    const float* __restrict__ xd,  const float* __restrict__ xmd,
    const float* __restrict__ eWih0, const float* __restrict__ eWhh0,
    const float* __restrict__ ebih0, const float* __restrict__ ebhh0,
    const float* __restrict__ eWih1, const float* __restrict__ eWhh1,
    const float* __restrict__ ebih1, const float* __restrict__ ebhh1,
    const float* __restrict__ dWih0, const float* __restrict__ dWhh0,
    const float* __restrict__ dbih0, const float* __restrict__ dbhh0,
    const float* __restrict__ dWih1, const float* __restrict__ dWhh1,
    const float* __restrict__ dbih1, const float* __restrict__ dbhh1,
    char* __restrict__ ws) {
  extern __shared__ char smem[];
  const int tid = threadIdx.x, bx = blockIdx.x;
  const int lane = tid & 63;
  const int w = tid >> 6;
  const int bg = w & 3, kslice = w >> 2;
  const int bs = bg << 4, kb0 = kslice << 4;
  const int u0 = bx << 2;

  unsigned* cnt = (unsigned*)ws;
  _Float16* h0p[2] = {(_Float16*)(ws + OFF_H0P0), (_Float16*)(ws + OFF_H0P0 + HB)};
  _Float16* eh1[2] = {(_Float16*)(ws + OFF_EH10), (_Float16*)(ws + OFF_EH10 + HB)};
  _Float16* dh1 = (_Float16*)(ws + OFF_DH1);
  const _Float16* wf = (const _Float16*)(ws + OFF_WF);
  const float* bf0 = (const float*)(ws + OFF_BF0);

  float hA = 0.f, hB = 0.f;
  unsigned ep = 0;

  // ---------- encoder weights -> LDS ----------
  fill_tile_f32(smem, L_TA0, eWhh0, u0, 0, 1, 2, -1, tid);   // gh0: r,z,nh | zeros
  fill_tile_f32(smem, L_TB0, eWih1, u0, 0, 1, -1, 2, tid);   // gi1: r,z | zeros | ni
  fill_tile_f32(smem, L_TB1, eWhh1, u0, 0, 1, 2, -1, tid);   // gh1: r,z,nh | zeros
  fill_small(smem, u0, tid, eWih0, ebih0, ebhh0, ebih1, ebhh1, nullptr);
  __syncthreads();

  for (int t = 0; t < TENC; ++t) {
    const int r = t & 1;
    f32x4 acc = gemm1(smem, L_TA0, h0p[r], kb0, lane, bs);
    epilogue(acc, smem, tid, L_BA, 1, xe, xme, t, TENC, u0, hA, h0p[r ^ 1]);
    gridbar(cnt, tid, bx, (++ep) * 32u);
    acc = gemm2(smem, L_TB0, L_TB1, h0p[r ^ 1], eh1[r], kb0, lane, bs);
    epilogue(acc, smem, tid, L_BB, 0, nullptr, nullptr, t, TENC, u0, hB,
             (t == TENC - 1) ? dh1 : eh1[r ^ 1]);
    gridbar(cnt, tid, bx, (++ep) * 32u);
  }

  // ---------- decoder weights -> LDS ----------
  fill_tile_f32(smem, L_TA0, dWhh0, u0, 0, 1, 2, -1, tid);
  fill_tile_f16(smem, L_TA1, wf,    u0, 0, 1, -1, 2, tid);   // Wf: r,z | zeros | ni
  fill_tile_f32(smem, L_TB0, dWih1, u0, 0, 1, -1, 2, tid);
  fill_tile_f32(smem, L_TB1, dWhh1, u0, 0, 1, 2, -1, tid);
  fill_small(smem, u0, tid, dWih0, dbih0, dbhh0, dbih1, dbhh1, bf0);
  __syncthreads();

  for (int t = 0; t < TDEC; ++t) {
    const int r = t & 1;   // parity continues seamlessly from encoder (192 even)
    f32x4 acc;
    if (t >= LBL) {
      acc = gemm2(smem, L_TA0, L_TA1, h0p[r], dh1 + (size_t)t * HE, kb0, lane, bs);
      epilogue(acc, smem, tid, L_BAA, 2, nullptr, xmd, t, TDEC, u0, hA, h0p[r ^ 1]);
    } else {
      acc = gemm1(smem, L_TA0, h0p[r], kb0, lane, bs);
      epilogue(acc, smem, tid, L_BA, 1, xd, xmd, t, TDEC, u0, hA, h0p[r ^ 1]);
    }
    gridbar(cnt, tid, bx, (++ep) * 32u);
    acc = gemm2(smem, L_TB0, L_TB1, h0p[r ^ 1], dh1 + (size_t)t * HE, kb0, lane, bs);
    epilogue(acc, smem, tid, L_BB, 0, nullptr, nullptr, t, TDEC, u0, hB,
             dh1 + (size_t)(t + 1) * HE);
    gridbar(cnt, tid, bx, (++ep) * 32u);
  }
}

// ---- epilogue projection: preds from stored h1 history (packed f16)
__global__ __launch_bounds__(64) void proj_kernel(const char* __restrict__ ws,
                                                  const float* __restrict__ outW,
                                                  const float* __restrict__ outb,
                                                  float* __restrict__ out) {
  const int ti = blockIdx.x / 7, c = blockIdx.x % 7;
  const _Float16* h = (const _Float16*)(ws + OFF_DH1) + (size_t)(LBL + 1 + ti) * HE;
  const int b = threadIdx.x;
  const float* wrow = outW + c * DM;
  float acc = outb[c];
#pragma unroll 4
  for (int k8 = 0; k8 < 128; ++k8) {
    const half8 hv = *(const half8*)(h + ((size_t)k8 * 64 + b) * 8);
    const float* wp = wrow + k8 * 8;
#pragma unroll
    for (int j = 0; j < 8; ++j) acc = fmaf((float)hv[j], wp[j], acc);
  }
  out[(size_t)b * (NPRED * 7) + ti * 7 + c] = acc;
}

extern "C" void kernel_launch(void* const* d_in, const int* in_sizes, int n_in,
                              void* d_out, int out_size, void* d_ws, size_t ws_size,
                              hipStream_t stream) {
  (void)in_sizes; (void)n_in; (void)out_size; (void)ws_size;
  const float* xe    = (const float*)d_in[0];
  const float* xme   = (const float*)d_in[1];
  const float* xd    = (const float*)d_in[2];
  const float* xmd   = (const float*)d_in[3];
  const float* eWih0 = (const float*)d_in[4];
  const float* eWhh0 = (const float*)d_in[5];
  const float* ebih0 = (const float*)d_in[6];
  const float* ebhh0 = (const float*)d_in[7];
  const float* eWih1 = (const float*)d_in[8];
  const float* eWhh1 = (const float*)d_in[9];
  const float* ebih1 = (const float*)d_in[10];
  const float* ebhh1 = (const float*)d_in[11];
  const float* dWih0 = (const float*)d_in[12];
  const float* dWhh0 = (const float*)d_in[13];
  const float* dbih0 = (const float*)d_in[14];
  const float* dbhh0 = (const float*)d_in[15];
  const float* dWih1 = (const float*)d_in[16];
  const float* dWhh1 = (const float*)d_in[17];
  const float* dbih1 = (const float*)d_in[18];
  const float* dbhh1 = (const float*)d_in[19];
  const float* outW  = (const float*)d_in[20];
  const float* outb  = (const float*)d_in[21];
  char* ws = (char*)d_ws;

  hipFuncSetAttribute(reinterpret_cast<const void*>(gru_persist),
                      hipFuncAttributeMaxDynamicSharedMemorySize, SMEM_BYTES);

  // zero: barrier counters + h0pack slot0 + encoder h1pack slot0
  hipMemsetAsync(ws, 0, OFF_H0P0 + HB, stream);
  hipMemsetAsync(ws + OFF_EH10, 0, HB, stream);

  prep_wf<<<3072, 256, 0, stream>>>(dWih0, dbih0, outW, outb, ws);
  gru_persist<<<256, 512, SMEM_BYTES, stream>>>(xe, xme, xd, xmd,
                                                eWih0, eWhh0, ebih0, ebhh0,
                                                eWih1, eWhh1, ebih1, ebhh1,
                                                dWih0, dWhh0, dbih0, dbhh0,
                                                dWih1, dWhh1, dbih1, dbhh1, ws);
  proj_kernel<<<NPRED * 7, 64, 0, stream>>>(ws, outW, outb, (float*)d_out);
}

// Round 3
// 36437.128 us; speedup vs baseline: 3.2611x; 1.0935x over previous
//
#include <hip/hip_runtime.h>
#include <math.h>

// GRU seq2seq on MI355X — Round 3: fix grid-barrier contention.
// Round 2 post-mortem: 49 us/barrier — all 8 counters in ONE cache line,
// 2048 spinners + 256 atomic adds serializing on it at L3.
// Round 3: two-level tree barrier (32 padded leaf counters -> root -> go word),
// only tid0 spins. Everything else identical to round 2.

typedef _Float16 half8 __attribute__((ext_vector_type(8)));
typedef _Float16 half4f __attribute__((ext_vector_type(4)));
typedef float f32x4 __attribute__((ext_vector_type(4)));

#define DM    1024
#define TENC  192
#define TDEC  216
#define LBL   48
#define NPRED 168
#define HB    131072            // one packed h buffer: 1024*64*2 bytes
#define HE    65536             // elements per h buffer

// workspace byte offsets
// [0,4096): 32 leaf counters, 128B stride | 4096: root | 4352: go
#define OFF_H0P0 8192
#define OFF_EH10 (OFF_H0P0 + 2*HB)
#define OFF_DH1  (OFF_EH10 + 2*HB)
#define OFF_WF   (OFF_DH1 + 217*HB)
#define OFF_BF0  (OFF_WF + 3072*1024*2)

// LDS byte offsets (dynamic shared, 140032 B total)
#define L_TA0 0
#define L_TA1 32768
#define L_TB0 65536
#define L_TB1 98304
#define L_XW  131072            // xw[3][4][12] f32 = 576 B
#define L_BA  131648            // 16 f32
#define L_BAA 131712            // 16 f32
#define L_BB  131776            // 16 f32
#define L_TR  131840            // 8 waves * 256 f32 = 8192 B
#define SMEM_BYTES (131840 + 8192)

__device__ __forceinline__ float sigm(float x) { return 1.0f / (1.0f + __expf(-x)); }

// ---- two-level grid barrier. 256 blocks = 32 leaves x 8 blocks.
// Leaf counters padded to own 128B lines; root and go on own lines.
// Monotone counters (no reset). Only tid0 spins (on the go word).
__device__ __forceinline__ void gridbar(unsigned* leaf, unsigned* root, unsigned* go,
                                        int tid, int bx, unsigned ep) {
  __syncthreads();
  if (tid == 0) {
    __threadfence();  // release: push our h-writes to the coherent point
    unsigned old = __hip_atomic_fetch_add(&leaf[(bx >> 3) << 5], 1u,
                                          __ATOMIC_ACQ_REL, __HIP_MEMORY_SCOPE_AGENT);
    if (old == ep * 8u - 1u) {          // last of my 8-block leaf
      unsigned r = __hip_atomic_fetch_add(root, 1u,
                                          __ATOMIC_ACQ_REL, __HIP_MEMORY_SCOPE_AGENT);
      if (r == ep * 32u - 1u) {         // last leaf overall
        __hip_atomic_store(go, ep, __ATOMIC_RELEASE, __HIP_MEMORY_SCOPE_AGENT);
      }
    }
    while (__hip_atomic_load(go, __ATOMIC_RELAXED, __HIP_MEMORY_SCOPE_AGENT) < ep)
      __builtin_amdgcn_s_sleep(4);
  }
  __syncthreads();
  __threadfence();  // acquire: invalidate stale cached h before reading
}

// ---- LDS tile fill: pack 16 rows (row map per 4-row gate group, -1 = zeros)
// into MFMA A-fragment order: elem((kb,quad,m),j) = ((kb*64 + quad*16 + m)*8 + j)
__device__ __forceinline__ void fill_tile_f32(char* smem, int off, const float* __restrict__ src,
                                              int u0, int g0, int g1, int g2, int g3, int tid) {
  const int w = tid >> 6, lane = tid & 63;
  int gsel[4] = {g0, g1, g2, g3};
#pragma unroll
  for (int mm = 0; mm < 2; ++mm) {
    const int m = w + mm * 8;
    const int g = gsel[m >> 2];
    const long srow = (g < 0) ? -1 : (long)g * DM + u0 + (m & 3);
#pragma unroll
    for (int p = 0; p < 4; ++p) {
      const int k = p * 256 + lane * 4;
      half4f hv;
      if (srow >= 0) {
        float4 v = *(const float4*)(src + srow * DM + k);
        hv = (half4f){(_Float16)v.x, (_Float16)v.y, (_Float16)v.z, (_Float16)v.w};
      } else {
        hv = (half4f){(_Float16)0.f, (_Float16)0.f, (_Float16)0.f, (_Float16)0.f};
      }
      const int kb = k >> 5, q = (k >> 3) & 3;
      const int elem = (kb * 64 + q * 16 + m) * 8 + (k & 7);
      *(half4f*)(smem + off + elem * 2) = hv;
    }
  }
}

__device__ __forceinline__ void fill_tile_f16(char* smem, int off, const _Float16* __restrict__ src,
                                              int u0, int g0, int g1, int g2, int g3, int tid) {
  const int w = tid >> 6, lane = tid & 63;
  int gsel[4] = {g0, g1, g2, g3};
#pragma unroll
  for (int mm = 0; mm < 2; ++mm) {
    const int m = w + mm * 8;
    const int g = gsel[m >> 2];
    const long srow = (g < 0) ? -1 : (long)g * DM + u0 + (m & 3);
#pragma unroll
    for (int p = 0; p < 4; ++p) {
      const int k = p * 256 + lane * 4;
      half4f hv;
      if (srow >= 0) hv = *(const half4f*)(src + srow * DM + k);
      else hv = (half4f){(_Float16)0.f, (_Float16)0.f, (_Float16)0.f, (_Float16)0.f};
      const int kb = k >> 5, q = (k >> 3) & 3;
      const int elem = (kb * 64 + q * 16 + m) * 8 + (k & 7);
      *(half4f*)(smem + off + elem * 2) = hv;
    }
  }
}

// small per-CU constants: x-side weight slice + fused biases
__device__ __forceinline__ void fill_small(char* smem, int u0, int tid,
    const float* __restrict__ Wih0, const float* __restrict__ bihA, const float* __restrict__ bhhA,
    const float* __restrict__ bih1, const float* __restrict__ bhh1, const float* __restrict__ bf0) {
  if (tid < 132) {
    const int rr = tid / 11, c = tid - rr * 11;
    const int g = rr >> 2, ul = rr & 3;
    ((float*)(smem + L_XW))[(g * 4 + ul) * 12 + c] = Wih0[(g * DM + u0 + ul) * 11 + c];
  }
  if (tid < 4) {
    const int u = u0 + tid;
    float* bA = (float*)(smem + L_BA);
    bA[tid] = bihA[u] + bhhA[u];
    bA[4 + tid] = bihA[DM + u] + bhhA[DM + u];
    bA[8 + tid] = bhhA[2 * DM + u];
    bA[12 + tid] = bihA[2 * DM + u];
    float* bB = (float*)(smem + L_BB);
    bB[tid] = bih1[u] + bhh1[u];
    bB[4 + tid] = bih1[DM + u] + bhh1[DM + u];
    bB[8 + tid] = bhh1[2 * DM + u];
    bB[12 + tid] = bih1[2 * DM + u];
    if (bf0) {
      float* bAa = (float*)(smem + L_BAA);
      bAa[tid] = bf0[u] + bhhA[u];
      bAa[4 + tid] = bf0[DM + u] + bhhA[DM + u];
      bAa[8 + tid] = bhhA[2 * DM + u];
      bAa[12 + tid] = bf0[2 * DM + u];
    }
  }
}

// ---- K-loop GEMMs. Wave covers batch group bs..bs+15 and K-slice kb0..kb0+15.
__device__ __forceinline__ f32x4 gemm1(const char* smem, int toff, const _Float16* __restrict__ bsrc,
                                       int kb0, int lane, int bs) {
  const half8* T = (const half8*)(smem + toff);
  const half8* Bp = (const half8*)bsrc + ((lane >> 4) << 6) + bs + (lane & 15);
  f32x4 a0 = (f32x4){0.f, 0.f, 0.f, 0.f}, a1 = a0;
#pragma unroll 4
  for (int kb = kb0; kb < kb0 + 16; kb += 2) {
    half8 x0 = T[(kb << 6) + lane];
    half8 y0 = Bp[(size_t)kb << 8];
    half8 x1 = T[((kb + 1) << 6) + lane];
    half8 y1 = Bp[(size_t)(kb + 1) << 8];
    a0 = __builtin_amdgcn_mfma_f32_16x16x32_f16(x0, y0, a0, 0, 0, 0);
    a1 = __builtin_amdgcn_mfma_f32_16x16x32_f16(x1, y1, a1, 0, 0, 0);
  }
  return a0 + a1;
}

__device__ __forceinline__ f32x4 gemm2(const char* smem, int t0, int t1,
                                       const _Float16* __restrict__ s0, const _Float16* __restrict__ s1,
                                       int kb0, int lane, int bs) {
  const half8* T0 = (const half8*)(smem + t0);
  const half8* T1 = (const half8*)(smem + t1);
  const int bidx = ((lane >> 4) << 6) + bs + (lane & 15);
  const half8* B0 = (const half8*)s0 + bidx;
  const half8* B1 = (const half8*)s1 + bidx;
  f32x4 a0 = (f32x4){0.f, 0.f, 0.f, 0.f}, a1 = a0;
#pragma unroll 4
  for (int kb = kb0; kb < kb0 + 16; ++kb) {
    half8 x0 = T0[(kb << 6) + lane];
    half8 y0 = B0[(size_t)kb << 8];
    half8 x1 = T1[(kb << 6) + lane];
    half8 y1 = B1[(size_t)kb << 8];
    a0 = __builtin_amdgcn_mfma_f32_16x16x32_f16(x0, y0, a0, 0, 0, 0);
    a1 = __builtin_amdgcn_mfma_f32_16x16x32_f16(x1, y1, a1, 0, 0, 0);
  }
  return a0 + a1;
}

// ---- gate epilogue. acc rows: [r*4 | z*4 | nh*4 | ni*4] (unit = reg index).
// xmode: 0 = none (phase B), 1 = full 7+4 inputs, 2 = marks only (autoreg).
__device__ __forceinline__ void epilogue(f32x4 acc, char* smem, int tid, int biasOff,
                                         int xmode, const float* __restrict__ xin,
                                         const float* __restrict__ xmk, int t, int seqT,
                                         int u0, float& hprev, _Float16* __restrict__ dst) {
  const int lane = tid & 63, w = tid >> 6;
  float* tr = (float*)(smem + L_TR) + (w << 8);
  const int quad = lane >> 4, col = lane & 15;
  tr[(quad * 4 + 0) * 16 + col] = acc[0];
  tr[(quad * 4 + 1) * 16 + col] = acc[1];
  tr[(quad * 4 + 2) * 16 + col] = acc[2];
  tr[(quad * 4 + 3) * 16 + col] = acc[3];
  __syncthreads();
  if (w < 4) {
    const float* trA = (const float*)(smem + L_TR) + (w << 8);
    const float* trB = trA + (4 << 8);
    const int ul = quad;
    const int b = (w << 4) + col;
    const int u = u0 + ul;
    float vr  = trA[ul * 16 + col]        + trB[ul * 16 + col];
    float vz  = trA[(4 + ul) * 16 + col]  + trB[(4 + ul) * 16 + col];
    float vnh = trA[(8 + ul) * 16 + col]  + trB[(8 + ul) * 16 + col];
    float vni = trA[(12 + ul) * 16 + col] + trB[(12 + ul) * 16 + col];
    const float* bias = (const float*)(smem + biasOff);
    const float* xw = (const float*)(smem + L_XW);
    float xr = 0.f, xz = 0.f, xn = 0.f;
    if (xmode == 1) {
      const float* xp = xin + (size_t)(b * seqT + t) * 7;
      const float* mp = xmk + (size_t)(b * seqT + t) * 4;
#pragma unroll
      for (int c = 0; c < 7; ++c) {
        float v = xp[c];
        xr = fmaf(xw[ul * 12 + c], v, xr);
        xz = fmaf(xw[(4 + ul) * 12 + c], v, xz);
        xn = fmaf(xw[(8 + ul) * 12 + c], v, xn);
      }
#pragma unroll
      for (int m = 0; m < 4; ++m) {
        float v = mp[m];
        xr = fmaf(xw[ul * 12 + 7 + m], v, xr);
        xz = fmaf(xw[(4 + ul) * 12 + 7 + m], v, xz);
        xn = fmaf(xw[(8 + ul) * 12 + 7 + m], v, xn);
      }
    } else if (xmode == 2) {
      const float* mp = xmk + (size_t)(b * seqT + t) * 4;
#pragma unroll
      for (int m = 0; m < 4; ++m) {
        float v = mp[m];
        xr = fmaf(xw[ul * 12 + 7 + m], v, xr);
        xz = fmaf(xw[(4 + ul) * 12 + 7 + m], v, xz);
        xn = fmaf(xw[(8 + ul) * 12 + 7 + m], v, xn);
      }
    }
    const float rp = vr + bias[ul] + xr;
    const float zp = vz + bias[4 + ul] + xz;
    const float rg = sigm(rp), zg = sigm(zp);
    const float np = (vni + bias[12 + ul] + xn) + rg * (vnh + bias[8 + ul]);
    const float ng = tanhf(np);
    const float hn = ng + zg * (hprev - ng);
    hprev = hn;
    dst[((u >> 3) * 64 + b) * 8 + (u & 7)] = (_Float16)hn;
  }
}

// ---- prep: Wf = dW_ih0[:, :7] @ out_W (f16), bf0 = db_ih0 + dW_ih0[:, :7] @ out_b
__global__ __launch_bounds__(256) void prep_wf(const float* __restrict__ dWih0,
                                               const float* __restrict__ dbih0,
                                               const float* __restrict__ outW,
                                               const float* __restrict__ outb,
                                               char* __restrict__ ws) {
  const int j = blockIdx.x;
  _Float16* wf = (_Float16*)(ws + OFF_WF);
  float* bf0 = (float*)(ws + OFF_BF0);
  float wrow[7];
#pragma unroll
  for (int c = 0; c < 7; ++c) wrow[c] = dWih0[j * 11 + c];
#pragma unroll
  for (int p = 0; p < 4; ++p) {
    const int k = p * 256 + threadIdx.x;
    float acc = 0.f;
#pragma unroll
    for (int c = 0; c < 7; ++c) acc = fmaf(wrow[c], outW[c * DM + k], acc);
    wf[(size_t)j * DM + k] = (_Float16)acc;
  }
  if (threadIdx.x == 0) {
    float bb = dbih0[j];
#pragma unroll
    for (int c = 0; c < 7; ++c) bb = fmaf(wrow[c], outb[c], bb);
    bf0[j] = bb;
  }
}

__global__ __launch_bounds__(512) void gru_persist(
    const float* __restrict__ xe,  const float* __restrict__ xme,
    const float* __restrict__ xd,  const float* __restrict__ xmd,
    const float* __restrict__ eWih0, const float* __restrict__ eWhh0,
    const float* __restrict__ ebih0, const float* __restrict__ ebhh0,
    const float* __restrict__ eWih1, const float* __restrict__ eWhh1,
    const float* __restrict__ ebih1, const float* __restrict__ ebhh1,
    const float* __restrict__ dWih0, const float* __restrict__ dWhh0,
    const float* __restrict__ dbih0, const float* __restrict__ dbhh0,
    const float* __restrict__ dWih1, const float* __restrict__ dWhh1,
    const float* __restrict__ dbih1, const float* __restrict__ dbhh1,
    char* __restrict__ ws) {
  extern __shared__ char smem[];
  const int tid = threadIdx.x, bx = blockIdx.x;
  const int lane = tid & 63;
  const int w = tid >> 6;
  const int bg = w & 3, kslice = w >> 2;
  const int bs = bg << 4, kb0 = kslice << 4;
  const int u0 = bx << 2;

  unsigned* leaf = (unsigned*)ws;
  unsigned* root = (unsigned*)(ws + 4096);
  unsigned* go   = (unsigned*)(ws + 4352);
  _Float16* h0p[2] = {(_Float16*)(ws + OFF_H0P0), (_Float16*)(ws + OFF_H0P0 + HB)};
  _Float16* eh1[2] = {(_Float16*)(ws + OFF_EH10), (_Float16*)(ws + OFF_EH10 + HB)};
  _Float16* dh1 = (_Float16*)(ws + OFF_DH1);
  const _Float16* wf = (const _Float16*)(ws + OFF_WF);
  const float* bf0 = (const float*)(ws + OFF_BF0);

  float hA = 0.f, hB = 0.f;
  unsigned ep = 0;

  // ---------- encoder weights -> LDS ----------
  fill_tile_f32(smem, L_TA0, eWhh0, u0, 0, 1, 2, -1, tid);   // gh0: r,z,nh | zeros
  fill_tile_f32(smem, L_TB0, eWih1, u0, 0, 1, -1, 2, tid);   // gi1: r,z | zeros | ni
  fill_tile_f32(smem, L_TB1, eWhh1, u0, 0, 1, 2, -1, tid);   // gh1: r,z,nh | zeros
  fill_small(smem, u0, tid, eWih0, ebih0, ebhh0, ebih1, ebhh1, nullptr);
  __syncthreads();

  for (int t = 0; t < TENC; ++t) {
    const int r = t & 1;
    f32x4 acc = gemm1(smem, L_TA0, h0p[r], kb0, lane, bs);
    epilogue(acc, smem, tid, L_BA, 1, xe, xme, t, TENC, u0, hA, h0p[r ^ 1]);
    gridbar(leaf, root, go, tid, bx, ++ep);
    acc = gemm2(smem, L_TB0, L_TB1, h0p[r ^ 1], eh1[r], kb0, lane, bs);
    epilogue(acc, smem, tid, L_BB, 0, nullptr, nullptr, t, TENC, u0, hB,
             (t == TENC - 1) ? dh1 : eh1[r ^ 1]);
    gridbar(leaf, root, go, tid, bx, ++ep);
  }

  // ---------- decoder weights -> LDS ----------
  fill_tile_f32(smem, L_TA0, dWhh0, u0, 0, 1, 2, -1, tid);
  fill_tile_f16(smem, L_TA1, wf,    u0, 0, 1, -1, 2, tid);   // Wf: r,z | zeros | ni
  fill_tile_f32(smem, L_TB0, dWih1, u0, 0, 1, -1, 2, tid);
  fill_tile_f32(smem, L_TB1, dWhh1, u0, 0, 1, 2, -1, tid);
  fill_small(smem, u0, tid, dWih0, dbih0, dbhh0, dbih1, dbhh1, bf0);
  __syncthreads();

  for (int t = 0; t < TDEC; ++t) {
    const int r = t & 1;   // parity continues seamlessly from encoder (192 even)
    f32x4 acc;
    if (t >= LBL) {
      acc = gemm2(smem, L_TA0, L_TA1, h0p[r], dh1 + (size_t)t * HE, kb0, lane, bs);
      epilogue(acc, smem, tid, L_BAA, 2, nullptr, xmd, t, TDEC, u0, hA, h0p[r ^ 1]);
    } else {
      acc = gemm1(smem, L_TA0, h0p[r], kb0, lane, bs);
      epilogue(acc, smem, tid, L_BA, 1, xd, xmd, t, TDEC, u0, hA, h0p[r ^ 1]);
    }
    gridbar(leaf, root, go, tid, bx, ++ep);
    acc = gemm2(smem, L_TB0, L_TB1, h0p[r ^ 1], dh1 + (size_t)t * HE, kb0, lane, bs);
    epilogue(acc, smem, tid, L_BB, 0, nullptr, nullptr, t, TDEC, u0, hB,
             dh1 + (size_t)(t + 1) * HE);
    gridbar(leaf, root, go, tid, bx, ++ep);
  }
}

// ---- epilogue projection: preds from stored h1 history (packed f16)
__global__ __launch_bounds__(64) void proj_kernel(const char* __restrict__ ws,
                                                  const float* __restrict__ outW,
                                                  const float* __restrict__ outb,
                                                  float* __restrict__ out) {
  const int ti = blockIdx.x / 7, c = blockIdx.x % 7;
  const _Float16* h = (const _Float16*)(ws + OFF_DH1) + (size_t)(LBL + 1 + ti) * HE;
  const int b = threadIdx.x;
  const float* wrow = outW + c * DM;
  float acc = outb[c];
#pragma unroll 4
  for (int k8 = 0; k8 < 128; ++k8) {
    const half8 hv = *(const half8*)(h + ((size_t)k8 * 64 + b) * 8);
    const float* wp = wrow + k8 * 8;
#pragma unroll
    for (int j = 0; j < 8; ++j) acc = fmaf((float)hv[j], wp[j], acc);
  }
  out[(size_t)b * (NPRED * 7) + ti * 7 + c] = acc;
}

extern "C" void kernel_launch(void* const* d_in, const int* in_sizes, int n_in,
                              void* d_out, int out_size, void* d_ws, size_t ws_size,
                              hipStream_t stream) {
  (void)in_sizes; (void)n_in; (void)out_size; (void)ws_size;
  const float* xe    = (const float*)d_in[0];
  const float* xme   = (const float*)d_in[1];
  const float* xd    = (const float*)d_in[2];
  const float* xmd   = (const float*)d_in[3];
  const float* eWih0 = (const float*)d_in[4];
  const float* eWhh0 = (const float*)d_in[5];
  const float* ebih0 = (const float*)d_in[6];
  const float* ebhh0 = (const float*)d_in[7];
  const float* eWih1 = (const float*)d_in[8];
  const float* eWhh1 = (const float*)d_in[9];
  const float* ebih1 = (const float*)d_in[10];
  const float* ebhh1 = (const float*)d_in[11];
  const float* dWih0 = (const float*)d_in[12];
  const float* dWhh0 = (const float*)d_in[13];
  const float* dbih0 = (const float*)d_in[14];
  const float* dbhh0 = (const float*)d_in[15];
  const float* dWih1 = (const float*)d_in[16];
  const float* dWhh1 = (const float*)d_in[17];
  const float* dbih1 = (const float*)d_in[18];
  const float* dbhh1 = (const float*)d_in[19];
  const float* outW  = (const float*)d_in[20];
  const float* outb  = (const float*)d_in[21];
  char* ws = (char*)d_ws;

  hipFuncSetAttribute(reinterpret_cast<const void*>(gru_persist),
                      hipFuncAttributeMaxDynamicSharedMemorySize, SMEM_BYTES);

  // zero: barrier counters/go + h0pack slot0 + encoder h1pack slot0
  hipMemsetAsync(ws, 0, OFF_H0P0 + HB, stream);
  hipMemsetAsync(ws + OFF_EH10, 0, HB, stream);

  prep_wf<<<3072, 256, 0, stream>>>(dWih0, dbih0, outW, outb, ws);
  gru_persist<<<256, 512, SMEM_BYTES, stream>>>(xe, xme, xd, xmd,
                                                eWih0, eWhh0, ebih0, ebhh0,
                                                eWih1, eWhh1, ebih1, ebhh1,
                                                dWih0, dWhh0, dbih0, dbhh0,
                                                dWih1, dWhh1, dbih1, dbhh1, ws);
  proj_kernel<<<NPRED * 7, 64, 0, stream>>>(ws, outW, outb, (float*)d_out);
}

// Round 4
// 6787.010 us; speedup vs baseline: 17.5076x; 5.3687x over previous
//
#include <hip/hip_runtime.h>
#include <math.h>

// GRU seq2seq on MI355X — Round 4: fence-free grid barrier.
// Round 3 post-mortem: 44 us/barrier was NOT arrival contention — it was
// agent-scope fences (__threadfence x2, one by ALL 8 waves) + ACQ_REL atomics,
// each emitting buffer_wbl2/buffer_inv (full per-XCD L2 scan) on gfx950.
// Round 4: per-access coherence. h stores = global_store sc0 sc1 (write-through
// to LLC, L2 never dirty). Barrier atomics RELAXED (no attached cache ops).
// go poll = raw sc0 sc1 load. Exactly one buffer_inv (acquire fence) per block
// per barrier, tid0 only. No wbl2 anywhere.

typedef _Float16 half8 __attribute__((ext_vector_type(8)));
typedef _Float16 half4f __attribute__((ext_vector_type(4)));
typedef float f32x4 __attribute__((ext_vector_type(4)));

#define DM    1024
#define TENC  192
#define TDEC  216
#define LBL   48
#define NPRED 168
#define HB    131072            // one packed h buffer: 1024*64*2 bytes
#define HE    65536             // elements per h buffer

// workspace byte offsets
// [0,4096): 32 leaf counters, 128B stride | 4096: root | 4352: go
#define OFF_H0P0 8192
#define OFF_EH10 (OFF_H0P0 + 2*HB)
#define OFF_DH1  (OFF_EH10 + 2*HB)
#define OFF_WF   (OFF_DH1 + 217*HB)
#define OFF_BF0  (OFF_WF + 3072*1024*2)

// LDS byte offsets (dynamic shared)
#define L_TA0 0
#define L_TA1 32768
#define L_TB0 65536
#define L_TB1 98304
#define L_XW  131072            // xw[3][4][12] f32 = 576 B
#define L_BA  131648            // 16 f32
#define L_BAA 131712            // 16 f32
#define L_BB  131776            // 16 f32
#define L_TR  131840            // 8 waves * 256 f32 = 8192 B
#define L_HST 140032            // h stage: 256 f16 = 512 B
#define SMEM_BYTES (140032 + 512)

__device__ __forceinline__ float sigm(float x) { return 1.0f / (1.0f + __expf(-x)); }

// ---- device-coherent (LLC-level) accesses: bypass the non-coherent per-XCD L2.
__device__ __forceinline__ void coh_store64(void* p, unsigned long long v) {
  asm volatile("global_store_dwordx2 %0, %1, off sc0 sc1\n\ts_waitcnt vmcnt(0)"
               :: "v"(p), "v"(v) : "memory");
}
__device__ __forceinline__ void coh_store32(void* p, unsigned v) {
  asm volatile("global_store_dword %0, %1, off sc0 sc1\n\ts_waitcnt vmcnt(0)"
               :: "v"(p), "v"(v) : "memory");
}
__device__ __forceinline__ unsigned coh_load32(const void* p) {
  unsigned r;
  asm volatile("global_load_dword %0, %1, off sc0 sc1\n\ts_waitcnt vmcnt(0)"
               : "=v"(r) : "v"(p) : "memory");
  return r;
}

// ---- fence-free two-level grid barrier. 256 blocks = 32 leaves x 8 blocks.
// Monotone relaxed counters; raw-coherent go word; single acquire-inv on exit.
// Producer ordering: h stores are sc0 sc1 with embedded vmcnt(0) wait, and the
// compiler drains vmcnt before s_barrier — so arrival implies h visible at LLC.
__device__ __forceinline__ void gridbar(unsigned* leaf, unsigned* root, unsigned* go,
                                        int tid, int bx, unsigned ep) {
  __syncthreads();
  if (tid == 0) {
    unsigned old = __hip_atomic_fetch_add(&leaf[(bx >> 3) << 5], 1u,
                                          __ATOMIC_RELAXED, __HIP_MEMORY_SCOPE_AGENT);
    if (old == ep * 8u - 1u) {          // last of my 8-block leaf
      unsigned r = __hip_atomic_fetch_add(root, 1u,
                                          __ATOMIC_RELAXED, __HIP_MEMORY_SCOPE_AGENT);
      if (r == ep * 32u - 1u) {         // last leaf overall
        coh_store32(go, ep);
      }
    }
    while (coh_load32(go) < ep) __builtin_amdgcn_s_sleep(1);
    // invalidate L1 + per-XCD L2 (no dirty lines exist -> cheap tag clear)
    __builtin_amdgcn_fence(__ATOMIC_ACQUIRE, "agent");
  }
  __syncthreads();
}

// ---- LDS tile fill: pack 16 rows (row map per 4-row gate group, -1 = zeros)
// into MFMA A-fragment order: elem((kb,quad,m),j) = ((kb*64 + quad*16 + m)*8 + j)
__device__ __forceinline__ void fill_tile_f32(char* smem, int off, const float* __restrict__ src,
                                              int u0, int g0, int g1, int g2, int g3, int tid) {
  const int w = tid >> 6, lane = tid & 63;
  int gsel[4] = {g0, g1, g2, g3};
#pragma unroll
  for (int mm = 0; mm < 2; ++mm) {
    const int m = w + mm * 8;
    const int g = gsel[m >> 2];
    const long srow = (g < 0) ? -1 : (long)g * DM + u0 + (m & 3);
#pragma unroll
    for (int p = 0; p < 4; ++p) {
      const int k = p * 256 + lane * 4;
      half4f hv;
      if (srow >= 0) {
        float4 v = *(const float4*)(src + srow * DM + k);
        hv = (half4f){(_Float16)v.x, (_Float16)v.y, (_Float16)v.z, (_Float16)v.w};
      } else {
        hv = (half4f){(_Float16)0.f, (_Float16)0.f, (_Float16)0.f, (_Float16)0.f};
      }
      const int kb = k >> 5, q = (k >> 3) & 3;
      const int elem = (kb * 64 + q * 16 + m) * 8 + (k & 7);
      *(half4f*)(smem + off + elem * 2) = hv;
    }
  }
}

__device__ __forceinline__ void fill_tile_f16(char* smem, int off, const _Float16* __restrict__ src,
                                              int u0, int g0, int g1, int g2, int g3, int tid) {
  const int w = tid >> 6, lane = tid & 63;
  int gsel[4] = {g0, g1, g2, g3};
#pragma unroll
  for (int mm = 0; mm < 2; ++mm) {
    const int m = w + mm * 8;
    const int g = gsel[m >> 2];
    const long srow = (g < 0) ? -1 : (long)g * DM + u0 + (m & 3);
#pragma unroll
    for (int p = 0; p < 4; ++p) {
      const int k = p * 256 + lane * 4;
      half4f hv;
      if (srow >= 0) hv = *(const half4f*)(src + srow * DM + k);
      else hv = (half4f){(_Float16)0.f, (_Float16)0.f, (_Float16)0.f, (_Float16)0.f};
      const int kb = k >> 5, q = (k >> 3) & 3;
      const int elem = (kb * 64 + q * 16 + m) * 8 + (k & 7);
      *(half4f*)(smem + off + elem * 2) = hv;
    }
  }
}

// small per-CU constants: x-side weight slice + fused biases
__device__ __forceinline__ void fill_small(char* smem, int u0, int tid,
    const float* __restrict__ Wih0, const float* __restrict__ bihA, const float* __restrict__ bhhA,
    const float* __restrict__ bih1, const float* __restrict__ bhh1, const float* __restrict__ bf0) {
  if (tid < 132) {
    const int rr = tid / 11, c = tid - rr * 11;
    const int g = rr >> 2, ul = rr & 3;
    ((float*)(smem + L_XW))[(g * 4 + ul) * 12 + c] = Wih0[(g * DM + u0 + ul) * 11 + c];
  }
  if (tid < 4) {
    const int u = u0 + tid;
    float* bA = (float*)(smem + L_BA);
    bA[tid] = bihA[u] + bhhA[u];
    bA[4 + tid] = bihA[DM + u] + bhhA[DM + u];
    bA[8 + tid] = bhhA[2 * DM + u];
    bA[12 + tid] = bihA[2 * DM + u];
    float* bB = (float*)(smem + L_BB);
    bB[tid] = bih1[u] + bhh1[u];
    bB[4 + tid] = bih1[DM + u] + bhh1[DM + u];
    bB[8 + tid] = bhh1[2 * DM + u];
    bB[12 + tid] = bih1[2 * DM + u];
    if (bf0) {
      float* bAa = (float*)(smem + L_BAA);
      bAa[tid] = bf0[u] + bhhA[u];
      bAa[4 + tid] = bf0[DM + u] + bhhA[DM + u];
      bAa[8 + tid] = bhhA[2 * DM + u];
      bAa[12 + tid] = bf0[2 * DM + u];
    }
  }
}

// ---- K-loop GEMMs. Wave covers batch group bs..bs+15 and K-slice kb0..kb0+15.
__device__ __forceinline__ f32x4 gemm1(const char* smem, int toff, const _Float16* __restrict__ bsrc,
                                       int kb0, int lane, int bs) {
  const half8* T = (const half8*)(smem + toff);
  const half8* Bp = (const half8*)bsrc + ((lane >> 4) << 6) + bs + (lane & 15);
  f32x4 a0 = (f32x4){0.f, 0.f, 0.f, 0.f}, a1 = a0;
#pragma unroll 4
  for (int kb = kb0; kb < kb0 + 16; kb += 2) {
    half8 x0 = T[(kb << 6) + lane];
    half8 y0 = Bp[(size_t)kb << 8];
    half8 x1 = T[((kb + 1) << 6) + lane];
    half8 y1 = Bp[(size_t)(kb + 1) << 8];
    a0 = __builtin_amdgcn_mfma_f32_16x16x32_f16(x0, y0, a0, 0, 0, 0);
    a1 = __builtin_amdgcn_mfma_f32_16x16x32_f16(x1, y1, a1, 0, 0, 0);
  }
  return a0 + a1;
}

__device__ __forceinline__ f32x4 gemm2(const char* smem, int t0, int t1,
                                       const _Float16* __restrict__ s0, const _Float16* __restrict__ s1,
                                       int kb0, int lane, int bs) {
  const half8* T0 = (const half8*)(smem + t0);
  const half8* T1 = (const half8*)(smem + t1);
  const int bidx = ((lane >> 4) << 6) + bs + (lane & 15);
  const half8* B0 = (const half8*)s0 + bidx;
  const half8* B1 = (const half8*)s1 + bidx;
  f32x4 a0 = (f32x4){0.f, 0.f, 0.f, 0.f}, a1 = a0;
#pragma unroll 4
  for (int kb = kb0; kb < kb0 + 16; ++kb) {
    half8 x0 = T0[(kb << 6) + lane];
    half8 y0 = B0[(size_t)kb << 8];
    half8 x1 = T1[(kb << 6) + lane];
    half8 y1 = B1[(size_t)kb << 8];
    a0 = __builtin_amdgcn_mfma_f32_16x16x32_f16(x0, y0, a0, 0, 0, 0);
    a1 = __builtin_amdgcn_mfma_f32_16x16x32_f16(x1, y1, a1, 0, 0, 0);
  }
  return a0 + a1;
}

// ---- gate epilogue. acc rows: [r*4 | z*4 | nh*4 | ni*4] (unit = reg index).
// xmode: 0 = none (phase B), 1 = full 7+4 inputs, 2 = marks only (autoreg).
// h_new staged through LDS; wave 0 does 8B device-coherent stores.
__device__ __forceinline__ void epilogue(f32x4 acc, char* smem, int tid, int biasOff,
                                         int xmode, const float* __restrict__ xin,
                                         const float* __restrict__ xmk, int t, int seqT,
                                         int u0, float& hprev, _Float16* __restrict__ dst) {
  const int lane = tid & 63, w = tid >> 6;
  float* tr = (float*)(smem + L_TR) + (w << 8);
  const int quad = lane >> 4, col = lane & 15;
  tr[(quad * 4 + 0) * 16 + col] = acc[0];
  tr[(quad * 4 + 1) * 16 + col] = acc[1];
  tr[(quad * 4 + 2) * 16 + col] = acc[2];
  tr[(quad * 4 + 3) * 16 + col] = acc[3];
  __syncthreads();
  if (w < 4) {
    const float* trA = (const float*)(smem + L_TR) + (w << 8);
    const float* trB = trA + (4 << 8);
    const int ul = quad;
    const int b = (w << 4) + col;
    float vr  = trA[ul * 16 + col]        + trB[ul * 16 + col];
    float vz  = trA[(4 + ul) * 16 + col]  + trB[(4 + ul) * 16 + col];
    float vnh = trA[(8 + ul) * 16 + col]  + trB[(8 + ul) * 16 + col];
    float vni = trA[(12 + ul) * 16 + col] + trB[(12 + ul) * 16 + col];
    const float* bias = (const float*)(smem + biasOff);
    const float* xw = (const float*)(smem + L_XW);
    float xr = 0.f, xz = 0.f, xn = 0.f;
    if (xmode == 1) {
      const float* xp = xin + (size_t)(b * seqT + t) * 7;
      const float* mp = xmk + (size_t)(b * seqT + t) * 4;
#pragma unroll
      for (int c = 0; c < 7; ++c) {
        float v = xp[c];
        xr = fmaf(xw[ul * 12 + c], v, xr);
        xz = fmaf(xw[(4 + ul) * 12 + c], v, xz);
        xn = fmaf(xw[(8 + ul) * 12 + c], v, xn);
      }
#pragma unroll
      for (int m = 0; m < 4; ++m) {
        float v = mp[m];
        xr = fmaf(xw[ul * 12 + 7 + m], v, xr);
        xz = fmaf(xw[(4 + ul) * 12 + 7 + m], v, xz);
        xn = fmaf(xw[(8 + ul) * 12 + 7 + m], v, xn);
      }
    } else if (xmode == 2) {
      const float* mp = xmk + (size_t)(b * seqT + t) * 4;
#pragma unroll
      for (int m = 0; m < 4; ++m) {
        float v = mp[m];
        xr = fmaf(xw[ul * 12 + 7 + m], v, xr);
        xz = fmaf(xw[(4 + ul) * 12 + 7 + m], v, xz);
        xn = fmaf(xw[(8 + ul) * 12 + 7 + m], v, xn);
      }
    }
    const float rp = vr + bias[ul] + xr;
    const float zp = vz + bias[4 + ul] + xz;
    const float rg = sigm(rp), zg = sigm(zp);
    const float np = (vni + bias[12 + ul] + xn) + rg * (vnh + bias[8 + ul]);
    const float ng = tanhf(np);
    const float hn = ng + zg * (hprev - ng);
    hprev = hn;
    ((_Float16*)(smem + L_HST))[b * 4 + ul] = (_Float16)hn;
  }
  __syncthreads();
  if (tid < 64) {
    unsigned long long v = *(const unsigned long long*)(smem + L_HST + tid * 8);
    char* gp = (char*)dst + (((size_t)(u0 >> 3)) * 64 + tid) * 16 + (size_t)(u0 & 7) * 2;
    coh_store64(gp, v);   // write-through to LLC + vmcnt(0)
  }
}

// ---- prep: Wf = dW_ih0[:, :7] @ out_W (f16), bf0 = db_ih0 + dW_ih0[:, :7] @ out_b
__global__ __launch_bounds__(256) void prep_wf(const float* __restrict__ dWih0,
                                               const float* __restrict__ dbih0,
                                               const float* __restrict__ outW,
                                               const float* __restrict__ outb,
                                               char* __restrict__ ws) {
  const int j = blockIdx.x;
  _Float16* wf = (_Float16*)(ws + OFF_WF);
  float* bf0 = (float*)(ws + OFF_BF0);
  float wrow[7];
#pragma unroll
  for (int c = 0; c < 7; ++c) wrow[c] = dWih0[j * 11 + c];
#pragma unroll
  for (int p = 0; p < 4; ++p) {
    const int k = p * 256 + threadIdx.x;
    float acc = 0.f;
#pragma unroll
    for (int c = 0; c < 7; ++c) acc = fmaf(wrow[c], outW[c * DM + k], acc);
    wf[(size_t)j * DM + k] = (_Float16)acc;
  }
  if (threadIdx.x == 0) {
    float bb = dbih0[j];
#pragma unroll
    for (int c = 0; c < 7; ++c) bb = fmaf(wrow[c], outb[c], bb);
    bf0[j] = bb;
  }
}

__global__ __launch_bounds__(512) void gru_persist(
    const float* __restrict__ xe,  const float* __restrict__ xme,
    const float* __restrict__ xd,  const float* __restrict__ xmd,
    const float* __restrict__ eWih0, const float* __restrict__ eWhh0,
    const float* __restrict__ ebih0, const float* __restrict__ ebhh0,
    const float* __restrict__ eWih1, const float* __restrict__ eWhh1,
    const float* __restrict__ ebih1, const float* __restrict__ ebhh1,
    const float* __restrict__ dWih0, const float* __restrict__ dWhh0,
    const float* __restrict__ dbih0, const float* __restrict__ dbhh0,
    const float* __restrict__ dWih1, const float* __restrict__ dWhh1,
    const float* __restrict__ dbih1, const float* __restrict__ dbhh1,
    char* __restrict__ ws) {
  extern __shared__ char smem[];
  const int tid = threadIdx.x, bx = blockIdx.x;
  const int lane = tid & 63;
  const int w = tid >> 6;
  const int bg = w & 3, kslice = w >> 2;
  const int bs = bg << 4, kb0 = kslice << 4;
  const int u0 = bx << 2;

  unsigned* leaf = (unsigned*)ws;
  unsigned* root = (unsigned*)(ws + 4096);
  unsigned* go   = (unsigned*)(ws + 4352);
  _Float16* h0p[2] = {(_Float16*)(ws + OFF_H0P0), (_Float16*)(ws + OFF_H0P0 + HB)};
  _Float16* eh1[2] = {(_Float16*)(ws + OFF_EH10), (_Float16*)(ws + OFF_EH10 + HB)};
  _Float16* dh1 = (_Float16*)(ws + OFF_DH1);
  const _Float16* wf = (const _Float16*)(ws + OFF_WF);
  const float* bf0 = (const float*)(ws + OFF_BF0);

  float hA = 0.f, hB = 0.f;
  unsigned ep = 0;

  // ---------- encoder weights -> LDS ----------
  fill_tile_f32(smem, L_TA0, eWhh0, u0, 0, 1, 2, -1, tid);   // gh0: r,z,nh | zeros
  fill_tile_f32(smem, L_TB0, eWih1, u0, 0, 1, -1, 2, tid);   // gi1: r,z | zeros | ni
  fill_tile_f32(smem, L_TB1, eWhh1, u0, 0, 1, 2, -1, tid);   // gh1: r,z,nh | zeros
  fill_small(smem, u0, tid, eWih0, ebih0, ebhh0, ebih1, ebhh1, nullptr);
  __syncthreads();

  for (int t = 0; t < TENC; ++t) {
    const int r = t & 1;
    f32x4 acc = gemm1(smem, L_TA0, h0p[r], kb0, lane, bs);
    epilogue(acc, smem, tid, L_BA, 1, xe, xme, t, TENC, u0, hA, h0p[r ^ 1]);
    gridbar(leaf, root, go, tid, bx, ++ep);
    acc = gemm2(smem, L_TB0, L_TB1, h0p[r ^ 1], eh1[r], kb0, lane, bs);
    epilogue(acc, smem, tid, L_BB, 0, nullptr, nullptr, t, TENC, u0, hB,
             (t == TENC - 1) ? dh1 : eh1[r ^ 1]);
    gridbar(leaf, root, go, tid, bx, ++ep);
  }

  // ---------- decoder weights -> LDS ----------
  fill_tile_f32(smem, L_TA0, dWhh0, u0, 0, 1, 2, -1, tid);
  fill_tile_f16(smem, L_TA1, wf,    u0, 0, 1, -1, 2, tid);   // Wf: r,z | zeros | ni
  fill_tile_f32(smem, L_TB0, dWih1, u0, 0, 1, -1, 2, tid);
  fill_tile_f32(smem, L_TB1, dWhh1, u0, 0, 1, 2, -1, tid);
  fill_small(smem, u0, tid, dWih0, dbih0, dbhh0, dbih1, dbhh1, bf0);
  __syncthreads();

  for (int t = 0; t < TDEC; ++t) {
    const int r = t & 1;   // parity continues seamlessly from encoder (192 even)
    f32x4 acc;
    if (t >= LBL) {
      acc = gemm2(smem, L_TA0, L_TA1, h0p[r], dh1 + (size_t)t * HE, kb0, lane, bs);
      epilogue(acc, smem, tid, L_BAA, 2, nullptr, xmd, t, TDEC, u0, hA, h0p[r ^ 1]);
    } else {
      acc = gemm1(smem, L_TA0, h0p[r], kb0, lane, bs);
      epilogue(acc, smem, tid, L_BA, 1, xd, xmd, t, TDEC, u0, hA, h0p[r ^ 1]);
    }
    gridbar(leaf, root, go, tid, bx, ++ep);
    acc = gemm2(smem, L_TB0, L_TB1, h0p[r ^ 1], dh1 + (size_t)t * HE, kb0, lane, bs);
    epilogue(acc, smem, tid, L_BB, 0, nullptr, nullptr, t, TDEC, u0, hB,
             dh1 + (size_t)(t + 1) * HE);
    gridbar(leaf, root, go, tid, bx, ++ep);
  }
}

// ---- epilogue projection: preds from stored h1 history (packed f16)
__global__ __launch_bounds__(64) void proj_kernel(const char* __restrict__ ws,
                                                  const float* __restrict__ outW,
                                                  const float* __restrict__ outb,
                                                  float* __restrict__ out) {
  const int ti = blockIdx.x / 7, c = blockIdx.x % 7;
  const _Float16* h = (const _Float16*)(ws + OFF_DH1) + (size_t)(LBL + 1 + ti) * HE;
  const int b = threadIdx.x;
  const float* wrow = outW + c * DM;
  float acc = outb[c];
#pragma unroll 4
  for (int k8 = 0; k8 < 128; ++k8) {
    const half8 hv = *(const half8*)(h + ((size_t)k8 * 64 + b) * 8);
    const float* wp = wrow + k8 * 8;
#pragma unroll
    for (int j = 0; j < 8; ++j) acc = fmaf((float)hv[j], wp[j], acc);
  }
  out[(size_t)b * (NPRED * 7) + ti * 7 + c] = acc;
}

extern "C" void kernel_launch(void* const* d_in, const int* in_sizes, int n_in,
                              void* d_out, int out_size, void* d_ws, size_t ws_size,
                              hipStream_t stream) {
  (void)in_sizes; (void)n_in; (void)out_size; (void)ws_size;
  const float* xe    = (const float*)d_in[0];
  const float* xme   = (const float*)d_in[1];
  const float* xd    = (const float*)d_in[2];
  const float* xmd   = (const float*)d_in[3];
  const float* eWih0 = (const float*)d_in[4];
  const float* eWhh0 = (const float*)d_in[5];
  const float* ebih0 = (const float*)d_in[6];
  const float* ebhh0 = (const float*)d_in[7];
  const float* eWih1 = (const float*)d_in[8];
  const float* eWhh1 = (const float*)d_in[9];
  const float* ebih1 = (const float*)d_in[10];
  const float* ebhh1 = (const float*)d_in[11];
  const float* dWih0 = (const float*)d_in[12];
  const float* dWhh0 = (const float*)d_in[13];
  const float* dbih0 = (const float*)d_in[14];
  const float* dbhh0 = (const float*)d_in[15];
  const float* dWih1 = (const float*)d_in[16];
  const float* dWhh1 = (const float*)d_in[17];
  const float* dbih1 = (const float*)d_in[18];
  const float* dbhh1 = (const float*)d_in[19];
  const float* outW  = (const float*)d_in[20];
  const float* outb  = (const float*)d_in[21];
  char* ws = (char*)d_ws;

  hipFuncSetAttribute(reinterpret_cast<const void*>(gru_persist),
                      hipFuncAttributeMaxDynamicSharedMemorySize, SMEM_BYTES);

  // zero: barrier counters/go + h0pack slot0 + encoder h1pack slot0
  hipMemsetAsync(ws, 0, OFF_H0P0 + HB, stream);
  hipMemsetAsync(ws + OFF_EH10, 0, HB, stream);

  prep_wf<<<3072, 256, 0, stream>>>(dWih0, dbih0, outW, outb, ws);
  gru_persist<<<256, 512, SMEM_BYTES, stream>>>(xe, xme, xd, xmd,
                                                eWih0, eWhh0, ebih0, ebhh0,
                                                eWih1, eWhh1, ebih1, ebhh1,
                                                dWih0, dWhh0, dbih0, dbhh0,
                                                dWih1, dWhh1, dbih1, dbhh1, ws);
  proj_kernel<<<NPRED * 7, 64, 0, stream>>>(ws, outW, outb, (float*)d_out);
}

// Round 5
// 6049.480 us; speedup vs baseline: 19.6421x; 1.1219x over previous
//
#include <hip/hip_runtime.h>
#include <math.h>

// GRU seq2seq on MI355X — Round 5: layer-pipelined merged intervals.
// Encoder + label region: L0(t) and L1(t-1) in ONE barrier interval
// (layer-0 chain is independent of layer-1 when inputs are teacher-forced).
// Autoreg region keeps 2 intervals/step (true feedback dependency).
// Barriers: 816 -> 578. Parallel epilogues (waves 0-3 = L0, waves 4-7 = L1),
// x-GEMV precomputed at interval start (overlaps h-load latency),
// single vmcnt drain at barrier entry. Coherence scheme from round 4
// (sc0 sc1 stores, relaxed tree barrier, one acquire-inv per block/interval).

typedef _Float16 half8 __attribute__((ext_vector_type(8)));
typedef _Float16 half4f __attribute__((ext_vector_type(4)));
typedef float f32x4 __attribute__((ext_vector_type(4)));

#define DM    1024
#define TENC  192
#define TDEC  216
#define LBL   48
#define NPRED 168
#define HB    131072            // one packed h buffer: 1024*64*2 bytes
#define HE    65536             // elements per h buffer

// workspace byte offsets
// [0,4096): 32 leaf counters, 128B stride | 4096: root | 4352: go
#define OFF_H0P0 8192
#define OFF_EH10 (OFF_H0P0 + 2*HB)
#define OFF_DH1  (OFF_EH10 + 2*HB)
#define OFF_WF   (OFF_DH1 + 217*HB)
#define OFF_BF0  (OFF_WF + 3072*1024*2)

// LDS byte offsets (dynamic shared)
#define L_TA0 0
#define L_TA1 32768
#define L_TB0 65536
#define L_TB1 98304
#define L_XW  131072            // xw[3][4][12] f32 = 576 B
#define L_BA  131648            // 16 f32
#define L_BAA 131712            // 16 f32
#define L_BB  131776            // 16 f32
#define L_TRA 131840            // 8 waves * 256 f32 = 8192 B
#define L_TRB 140032            // 8192 B
#define L_HSTA 148224           // 256 f16 = 512 B
#define L_HSTB 148736           // 512 B
#define SMEM_BYTES 149248

__device__ __forceinline__ float sigm(float x) { return 1.0f / (1.0f + __expf(-x)); }

// ---- device-coherent (LLC-level) accesses: bypass the non-coherent per-XCD L2.
__device__ __forceinline__ void coh_store64(void* p, unsigned long long v) {
  asm volatile("global_store_dwordx2 %0, %1, off sc0 sc1" :: "v"(p), "v"(v) : "memory");
}
__device__ __forceinline__ void coh_store32(void* p, unsigned v) {
  asm volatile("global_store_dword %0, %1, off sc0 sc1\n\ts_waitcnt vmcnt(0)"
               :: "v"(p), "v"(v) : "memory");
}
__device__ __forceinline__ unsigned coh_load32(const void* p) {
  unsigned r;
  asm volatile("global_load_dword %0, %1, off sc0 sc1\n\ts_waitcnt vmcnt(0)"
               : "=v"(r) : "v"(p) : "memory");
  return r;
}

// ---- fence-free two-level grid barrier. 256 blocks = 32 leaves x 8 blocks.
// Entry: drain this wave's outstanding coherent stores, then s_barrier (so all
// of the block's h-stores are at LLC before tid0 arrives). Monotone relaxed
// counters; raw-coherent go word; single acquire-inv (L1+L2) per block on exit.
__device__ __forceinline__ void gridbar(unsigned* leaf, unsigned* root, unsigned* go,
                                        int tid, int bx, unsigned ep) {
  asm volatile("s_waitcnt vmcnt(0)" ::: "memory");
  __syncthreads();
  if (tid == 0) {
    unsigned old = __hip_atomic_fetch_add(&leaf[(bx >> 3) << 5], 1u,
                                          __ATOMIC_RELAXED, __HIP_MEMORY_SCOPE_AGENT);
    if (old == ep * 8u - 1u) {
      unsigned r = __hip_atomic_fetch_add(root, 1u,
                                          __ATOMIC_RELAXED, __HIP_MEMORY_SCOPE_AGENT);
      if (r == ep * 32u - 1u) {
        coh_store32(go, ep);
      }
    }
    while (coh_load32(go) < ep) __builtin_amdgcn_s_sleep(1);
    __builtin_amdgcn_fence(__ATOMIC_ACQUIRE, "agent");  // inv L1+L2 (no dirty lines)
  }
  __syncthreads();
}

// ---- LDS tile fill: pack 16 rows (row map per 4-row gate group, -1 = zeros)
// into MFMA A-fragment order: elem((kb,quad,m),j) = ((kb*64 + quad*16 + m)*8 + j)
__device__ __forceinline__ void fill_tile_f32(char* smem, int off, const float* __restrict__ src,
                                              int u0, int g0, int g1, int g2, int g3, int tid) {
  const int w = tid >> 6, lane = tid & 63;
  int gsel[4] = {g0, g1, g2, g3};
#pragma unroll
  for (int mm = 0; mm < 2; ++mm) {
    const int m = w + mm * 8;
    const int g = gsel[m >> 2];
    const long srow = (g < 0) ? -1 : (long)g * DM + u0 + (m & 3);
#pragma unroll
    for (int p = 0; p < 4; ++p) {
      const int k = p * 256 + lane * 4;
      half4f hv;
      if (srow >= 0) {
        float4 v = *(const float4*)(src + srow * DM + k);
        hv = (half4f){(_Float16)v.x, (_Float16)v.y, (_Float16)v.z, (_Float16)v.w};
      } else {
        hv = (half4f){(_Float16)0.f, (_Float16)0.f, (_Float16)0.f, (_Float16)0.f};
      }
      const int kb = k >> 5, q = (k >> 3) & 3;
      const int elem = (kb * 64 + q * 16 + m) * 8 + (k & 7);
      *(half4f*)(smem + off + elem * 2) = hv;
    }
  }
}

__device__ __forceinline__ void fill_tile_f16(char* smem, int off, const _Float16* __restrict__ src,
                                              int u0, int g0, int g1, int g2, int g3, int tid) {
  const int w = tid >> 6, lane = tid & 63;
  int gsel[4] = {g0, g1, g2, g3};
#pragma unroll
  for (int mm = 0; mm < 2; ++mm) {
    const int m = w + mm * 8;
    const int g = gsel[m >> 2];
    const long srow = (g < 0) ? -1 : (long)g * DM + u0 + (m & 3);
#pragma unroll
    for (int p = 0; p < 4; ++p) {
      const int k = p * 256 + lane * 4;
      half4f hv;
      if (srow >= 0) hv = *(const half4f*)(src + srow * DM + k);
      else hv = (half4f){(_Float16)0.f, (_Float16)0.f, (_Float16)0.f, (_Float16)0.f};
      const int kb = k >> 5, q = (k >> 3) & 3;
      const int elem = (kb * 64 + q * 16 + m) * 8 + (k & 7);
      *(half4f*)(smem + off + elem * 2) = hv;
    }
  }
}

// small per-CU constants: x-side weight slice + fused biases
__device__ __forceinline__ void fill_small(char* smem, int u0, int tid,
    const float* __restrict__ Wih0, const float* __restrict__ bihA, const float* __restrict__ bhhA,
    const float* __restrict__ bih1, const float* __restrict__ bhh1, const float* __restrict__ bf0) {
  if (tid < 132) {
    const int rr = tid / 11, c = tid - rr * 11;
    const int g = rr >> 2, ul = rr & 3;
    ((float*)(smem + L_XW))[(g * 4 + ul) * 12 + c] = Wih0[(g * DM + u0 + ul) * 11 + c];
  }
  if (tid < 4) {
    const int u = u0 + tid;
    float* bA = (float*)(smem + L_BA);
    bA[tid] = bihA[u] + bhhA[u];
    bA[4 + tid] = bihA[DM + u] + bhhA[DM + u];
    bA[8 + tid] = bhhA[2 * DM + u];
    bA[12 + tid] = bihA[2 * DM + u];
    float* bB = (float*)(smem + L_BB);
    bB[tid] = bih1[u] + bhh1[u];
    bB[4 + tid] = bih1[DM + u] + bhh1[DM + u];
    bB[8 + tid] = bhh1[2 * DM + u];
    bB[12 + tid] = bih1[2 * DM + u];
    if (bf0) {
      float* bAa = (float*)(smem + L_BAA);
      bAa[tid] = bf0[u] + bhhA[u];
      bAa[4 + tid] = bf0[DM + u] + bhhA[DM + u];
      bAa[8 + tid] = bhhA[2 * DM + u];
      bAa[12 + tid] = bf0[2 * DM + u];
    }
  }
}

// ---- K-loop GEMMs. Wave covers batch group bs..bs+15 and K-slice kb0..kb0+15.
__device__ __forceinline__ f32x4 gemm1(const char* smem, int toff, const _Float16* __restrict__ bsrc,
                                       int kb0, int lane, int bs) {
  const half8* T = (const half8*)(smem + toff);
  const half8* Bp = (const half8*)bsrc + ((lane >> 4) << 6) + bs + (lane & 15);
  f32x4 a0 = (f32x4){0.f, 0.f, 0.f, 0.f}, a1 = a0;
#pragma unroll 4
  for (int kb = kb0; kb < kb0 + 16; kb += 2) {
    half8 x0 = T[(kb << 6) + lane];
    half8 y0 = Bp[(size_t)kb << 8];
    half8 x1 = T[((kb + 1) << 6) + lane];
    half8 y1 = Bp[(size_t)(kb + 1) << 8];
    a0 = __builtin_amdgcn_mfma_f32_16x16x32_f16(x0, y0, a0, 0, 0, 0);
    a1 = __builtin_amdgcn_mfma_f32_16x16x32_f16(x1, y1, a1, 0, 0, 0);
  }
  return a0 + a1;
}

__device__ __forceinline__ f32x4 gemm2(const char* smem, int t0, int t1,
                                       const _Float16* __restrict__ s0, const _Float16* __restrict__ s1,
                                       int kb0, int lane, int bs) {
  const half8* T0 = (const half8*)(smem + t0);
  const half8* T1 = (const half8*)(smem + t1);
  const int bidx = ((lane >> 4) << 6) + bs + (lane & 15);
  const half8* B0 = (const half8*)s0 + bidx;
  const half8* B1 = (const half8*)s1 + bidx;
  f32x4 a0 = (f32x4){0.f, 0.f, 0.f, 0.f}, a1 = a0;
#pragma unroll 4
  for (int kb = kb0; kb < kb0 + 16; ++kb) {
    half8 x0 = T0[(kb << 6) + lane];
    half8 y0 = B0[(size_t)kb << 8];
    half8 x1 = T1[(kb << 6) + lane];
    half8 y1 = B1[(size_t)kb << 8];
    a0 = __builtin_amdgcn_mfma_f32_16x16x32_f16(x0, y0, a0, 0, 0, 0);
    a1 = __builtin_amdgcn_mfma_f32_16x16x32_f16(x1, y1, a1, 0, 0, 0);
  }
  return a0 + a1;
}

// ---- write acc to a TR region (all 8 waves)
__device__ __forceinline__ void tr_store(char* smem, int trOff, int w, int lane, f32x4 acc) {
  float* tr = (float*)(smem + trOff) + (w << 8);
  const int quad = lane >> 4, col = lane & 15;
  tr[(quad * 4 + 0) * 16 + col] = acc[0];
  tr[(quad * 4 + 1) * 16 + col] = acc[1];
  tr[(quad * 4 + 2) * 16 + col] = acc[2];
  tr[(quad * 4 + 3) * 16 + col] = acc[3];
}

// ---- x-side GEMV precompute (runs BEFORE the gemms; loads overlap h-loads).
// xmode 1: 7 inputs + 4 marks; xmode 2: marks only (autoreg, Wf-folded).
__device__ __forceinline__ void x_pre(const char* smem, int xmode,
    const float* __restrict__ xin, const float* __restrict__ xmk,
    int t, int seqT, int b, int ul, float& xr, float& xz, float& xn) {
  const float* xw = (const float*)(smem + L_XW);
  xr = 0.f; xz = 0.f; xn = 0.f;
  if (xmode == 1) {
    const float* xp = xin + (size_t)(b * seqT + t) * 7;
#pragma unroll
    for (int c = 0; c < 7; ++c) {
      float v = xp[c];
      xr = fmaf(xw[ul * 12 + c], v, xr);
      xz = fmaf(xw[(4 + ul) * 12 + c], v, xz);
      xn = fmaf(xw[(8 + ul) * 12 + c], v, xn);
    }
  }
  const float* mp = xmk + (size_t)(b * seqT + t) * 4;
#pragma unroll
  for (int m = 0; m < 4; ++m) {
    float v = mp[m];
    xr = fmaf(xw[ul * 12 + 7 + m], v, xr);
    xz = fmaf(xw[(4 + ul) * 12 + 7 + m], v, xz);
    xn = fmaf(xw[(8 + ul) * 12 + 7 + m], v, xn);
  }
}

// ---- gate epilogue math for one wave group (wb=0: waves0-3, wb=4: waves4-7).
__device__ __forceinline__ void epi(char* smem, int trOff, int stOff, int wb,
                                    int biasOff, float pxr, float pxz, float pxn,
                                    int tid, float& hprev) {
  const int lane = tid & 63, w = tid >> 6;
  const int bg = w - wb;
  const int col = lane & 15, ul = lane >> 4;
  const float* t0 = (const float*)(smem + trOff) + (bg << 8);
  const float* t1 = t0 + (4 << 8);
  const int b = (bg << 4) + col;
  float vr  = t0[ul * 16 + col]        + t1[ul * 16 + col];
  float vz  = t0[(4 + ul) * 16 + col]  + t1[(4 + ul) * 16 + col];
  float vnh = t0[(8 + ul) * 16 + col]  + t1[(8 + ul) * 16 + col];
  float vni = t0[(12 + ul) * 16 + col] + t1[(12 + ul) * 16 + col];
  const float* bias = (const float*)(smem + biasOff);
  float rg = sigm(vr + bias[ul] + pxr);
  float zg = sigm(vz + bias[4 + ul] + pxz);
  float ng = tanhf((vni + bias[12 + ul] + pxn) + rg * (vnh + bias[8 + ul]));
  float hn = ng + zg * (hprev - ng);
  hprev = hn;
  ((_Float16*)(smem + stOff))[b * 4 + ul] = (_Float16)hn;
}

// ---- coherent 8B store of a 512B stage region (one wave: i = 0..63)
__device__ __forceinline__ void st8(_Float16* dst, int u0, int i, const char* stage) {
  unsigned long long v = *(const unsigned long long*)(stage + i * 8);
  char* gp = (char*)dst + (((size_t)(u0 >> 3)) * 64 + i) * 16 + (size_t)(u0 & 7) * 2;
  coh_store64(gp, v);
}

// ---- prep: Wf = dW_ih0[:, :7] @ out_W (f16), bf0 = db_ih0 + dW_ih0[:, :7] @ out_b
__global__ __launch_bounds__(256) void prep_wf(const float* __restrict__ dWih0,
                                               const float* __restrict__ dbih0,
                                               const float* __restrict__ outW,
                                               const float* __restrict__ outb,
                                               char* __restrict__ ws) {
  const int j = blockIdx.x;
  _Float16* wf = (_Float16*)(ws + OFF_WF);
  float* bf0 = (float*)(ws + OFF_BF0);
  float wrow[7];
#pragma unroll
  for (int c = 0; c < 7; ++c) wrow[c] = dWih0[j * 11 + c];
#pragma unroll
  for (int p = 0; p < 4; ++p) {
    const int k = p * 256 + threadIdx.x;
    float acc = 0.f;
#pragma unroll
    for (int c = 0; c < 7; ++c) acc = fmaf(wrow[c], outW[c * DM + k], acc);
    wf[(size_t)j * DM + k] = (_Float16)acc;
  }
  if (threadIdx.x == 0) {
    float bb = dbih0[j];
#pragma unroll
    for (int c = 0; c < 7; ++c) bb = fmaf(wrow[c], outb[c], bb);
    bf0[j] = bb;
  }
}

__global__ __launch_bounds__(512) void gru_persist(
    const float* __restrict__ xe,  const float* __restrict__ xme,
    const float* __restrict__ xd,  const float* __restrict__ xmd,
    const float* __restrict__ eWih0, const float* __restrict__ eWhh0,
    const float* __restrict__ ebih0, const float* __restrict__ ebhh0,
    const float* __restrict__ eWih1, const float* __restrict__ eWhh1,
    const float* __restrict__ ebih1, const float* __restrict__ ebhh1,
    const float* __restrict__ dWih0, const float* __restrict__ dWhh0,
    const float* __restrict__ dbih0, const float* __restrict__ dbhh0,
    const float* __restrict__ dWih1, const float* __restrict__ dWhh1,
    const float* __restrict__ dbih1, const float* __restrict__ dbhh1,
    char* __restrict__ ws) {
  extern __shared__ char smem[];
  const int tid = threadIdx.x, bx = blockIdx.x;
  const int lane = tid & 63;
  const int w = tid >> 6;
  const int bg = w & 3, kslice = w >> 2;
  const int bs = bg << 4, kb0 = kslice << 4;
  const int u0 = bx << 2;
  // epilogue-thread coords (valid within the active wave group)
  const int bA = ((w & 3) << 4) + (lane & 15);
  const int ulA = lane >> 4;

  unsigned* leaf = (unsigned*)ws;
  unsigned* root = (unsigned*)(ws + 4096);
  unsigned* go   = (unsigned*)(ws + 4352);
  _Float16* h0p[2] = {(_Float16*)(ws + OFF_H0P0), (_Float16*)(ws + OFF_H0P0 + HB)};
  _Float16* eh1[2] = {(_Float16*)(ws + OFF_EH10), (_Float16*)(ws + OFF_EH10 + HB)};
  _Float16* dh1 = (_Float16*)(ws + OFF_DH1);
  const _Float16* wf = (const _Float16*)(ws + OFF_WF);
  const float* bf0 = (const float*)(ws + OFF_BF0);

  float hA = 0.f, hB = 0.f;
  unsigned ep = 0;

  // ---------- encoder weights -> LDS ----------
  fill_tile_f32(smem, L_TA0, eWhh0, u0, 0, 1, 2, -1, tid);   // gh0: r,z,nh | zeros
  fill_tile_f32(smem, L_TB0, eWih1, u0, 0, 1, -1, 2, tid);   // gi1: r,z | zeros | ni
  fill_tile_f32(smem, L_TB1, eWhh1, u0, 0, 1, 2, -1, tid);   // gh1: r,z,nh | zeros
  fill_small(smem, u0, tid, eWih0, ebih0, ebhh0, ebih1, ebhh1, nullptr);
  __syncthreads();

  // ---------- encoder: merged intervals t = 0..191: L0(t) + L1(t-1) ----------
  for (int t = 0; t < TENC; ++t) {
    const int r = t & 1;
    float pxr, pxz, pxn;
    if (w < 4) x_pre(smem, 1, xe, xme, t, TENC, bA, ulA, pxr, pxz, pxn);
    f32x4 aA = gemm1(smem, L_TA0, h0p[r], kb0, lane, bs);
    f32x4 aB;
    if (t > 0) aB = gemm2(smem, L_TB0, L_TB1, h0p[r], eh1[(t - 1) & 1], kb0, lane, bs);
    tr_store(smem, L_TRA, w, lane, aA);
    if (t > 0) tr_store(smem, L_TRB, w, lane, aB);
    __syncthreads();
    if (w < 4) epi(smem, L_TRA, L_HSTA, 0, L_BA, pxr, pxz, pxn, tid, hA);
    else if (t > 0) epi(smem, L_TRB, L_HSTB, 4, L_BB, 0.f, 0.f, 0.f, tid, hB);
    __syncthreads();
    if (tid < 64) st8(h0p[r ^ 1], u0, tid, smem + L_HSTA);
    else if (t > 0 && tid < 128) st8(eh1[t & 1], u0, tid - 64, smem + L_HSTB);
    gridbar(leaf, root, go, tid, bx, ++ep);
  }
  // drain: L1e(191) -> dh1[0]  (h0(191) is in h0p[0]; h1(190) in eh1[1])
  {
    f32x4 aB = gemm2(smem, L_TB0, L_TB1, h0p[0], eh1[1], kb0, lane, bs);
    tr_store(smem, L_TRB, w, lane, aB);
    __syncthreads();
    if (w >= 4) epi(smem, L_TRB, L_HSTB, 4, L_BB, 0.f, 0.f, 0.f, tid, hB);
    __syncthreads();
    if (tid >= 64 && tid < 128) st8(dh1, u0, tid - 64, smem + L_HSTB);
    gridbar(leaf, root, go, tid, bx, ++ep);
  }

  // ---------- decoder weights -> LDS ----------
  fill_tile_f32(smem, L_TA0, dWhh0, u0, 0, 1, 2, -1, tid);
  fill_tile_f16(smem, L_TA1, wf,    u0, 0, 1, -1, 2, tid);   // Wf: r,z | zeros | ni
  fill_tile_f32(smem, L_TB0, dWih1, u0, 0, 1, -1, 2, tid);
  fill_tile_f32(smem, L_TB1, dWhh1, u0, 0, 1, 2, -1, tid);
  fill_small(smem, u0, tid, dWih0, dbih0, dbhh0, dbih1, dbhh1, bf0);
  __syncthreads();

  // ---------- label region: merged intervals d = 0..47: L0d(d) + L1d(d-1) ----------
  for (int d = 0; d < LBL; ++d) {
    const int r = d & 1;
    float pxr, pxz, pxn;
    if (w < 4) x_pre(smem, 1, xd, xmd, d, TDEC, bA, ulA, pxr, pxz, pxn);
    f32x4 aA = gemm1(smem, L_TA0, h0p[r], kb0, lane, bs);
    f32x4 aB;
    if (d > 0) aB = gemm2(smem, L_TB0, L_TB1, h0p[r], dh1 + (size_t)(d - 1) * HE, kb0, lane, bs);
    tr_store(smem, L_TRA, w, lane, aA);
    if (d > 0) tr_store(smem, L_TRB, w, lane, aB);
    __syncthreads();
    if (w < 4) epi(smem, L_TRA, L_HSTA, 0, L_BA, pxr, pxz, pxn, tid, hA);
    else if (d > 0) epi(smem, L_TRB, L_HSTB, 4, L_BB, 0.f, 0.f, 0.f, tid, hB);
    __syncthreads();
    if (tid < 64) st8(h0p[r ^ 1], u0, tid, smem + L_HSTA);
    else if (d > 0 && tid < 128) st8(dh1 + (size_t)d * HE, u0, tid - 64, smem + L_HSTB);
    gridbar(leaf, root, go, tid, bx, ++ep);
  }
  // drain: L1d(47) -> dh1[48]  (h0d(47) in h0p[0]; h-side dh1[47])
  {
    f32x4 aB = gemm2(smem, L_TB0, L_TB1, h0p[0], dh1 + (size_t)47 * HE, kb0, lane, bs);
    tr_store(smem, L_TRB, w, lane, aB);
    __syncthreads();
    if (w >= 4) epi(smem, L_TRB, L_HSTB, 4, L_BB, 0.f, 0.f, 0.f, tid, hB);
    __syncthreads();
    if (tid >= 64 && tid < 128) st8(dh1 + (size_t)48 * HE, u0, tid - 64, smem + L_HSTB);
    gridbar(leaf, root, go, tid, bx, ++ep);
  }

  // ---------- autoregressive region: s = 48..215, 2 intervals/step ----------
  for (int s = LBL; s < TDEC; ++s) {
    const int r = s & 1;
    // A-interval: h0(s) = L0(h0(s-1), Wf·h1(s-1) + marks)
    {
      float pxr, pxz, pxn;
      if (w < 4) x_pre(smem, 2, nullptr, xmd, s, TDEC, bA, ulA, pxr, pxz, pxn);
      f32x4 aA = gemm2(smem, L_TA0, L_TA1, h0p[r], dh1 + (size_t)s * HE, kb0, lane, bs);
      tr_store(smem, L_TRA, w, lane, aA);
      __syncthreads();
      if (w < 4) epi(smem, L_TRA, L_HSTA, 0, L_BAA, pxr, pxz, pxn, tid, hA);
      __syncthreads();
      if (tid < 64) st8(h0p[r ^ 1], u0, tid, smem + L_HSTA);
      gridbar(leaf, root, go, tid, bx, ++ep);
    }
    // B-interval: h1(s) = L1(h0(s), h1(s-1)) -> dh1[s+1]
    {
      f32x4 aB = gemm2(smem, L_TB0, L_TB1, h0p[r ^ 1], dh1 + (size_t)s * HE, kb0, lane, bs);
      tr_store(smem, L_TRB, w, lane, aB);
      __syncthreads();
      if (w >= 4) epi(smem, L_TRB, L_HSTB, 4, L_BB, 0.f, 0.f, 0.f, tid, hB);
      __syncthreads();
      if (tid >= 64 && tid < 128) st8(dh1 + (size_t)(s + 1) * HE, u0, tid - 64, smem + L_HSTB);
      gridbar(leaf, root, go, tid, bx, ++ep);
    }
  }
}

// ---- epilogue projection: preds from stored h1 history (packed f16)
__global__ __launch_bounds__(64) void proj_kernel(const char* __restrict__ ws,
                                                  const float* __restrict__ outW,
                                                  const float* __restrict__ outb,
                                                  float* __restrict__ out) {
  const int ti = blockIdx.x / 7, c = blockIdx.x % 7;
  const _Float16* h = (const _Float16*)(ws + OFF_DH1) + (size_t)(LBL + 1 + ti) * HE;
  const int b = threadIdx.x;
  const float* wrow = outW + c * DM;
  float acc = outb[c];
#pragma unroll 4
  for (int k8 = 0; k8 < 128; ++k8) {
    const half8 hv = *(const half8*)(h + ((size_t)k8 * 64 + b) * 8);
    const float* wp = wrow + k8 * 8;
#pragma unroll
    for (int j = 0; j < 8; ++j) acc = fmaf((float)hv[j], wp[j], acc);
  }
  out[(size_t)b * (NPRED * 7) + ti * 7 + c] = acc;
}

extern "C" void kernel_launch(void* const* d_in, const int* in_sizes, int n_in,
                              void* d_out, int out_size, void* d_ws, size_t ws_size,
                              hipStream_t stream) {
  (void)in_sizes; (void)n_in; (void)out_size; (void)ws_size;
  const float* xe    = (const float*)d_in[0];
  const float* xme   = (const float*)d_in[1];
  const float* xd    = (const float*)d_in[2];
  const float* xmd   = (const float*)d_in[3];
  const float* eWih0 = (const float*)d_in[4];
  const float* eWhh0 = (const float*)d_in[5];
  const float* ebih0 = (const float*)d_in[6];
  const float* ebhh0 = (const float*)d_in[7];
  const float* eWih1 = (const float*)d_in[8];
  const float* eWhh1 = (const float*)d_in[9];
  const float* ebih1 = (const float*)d_in[10];
  const float* ebhh1 = (const float*)d_in[11];
  const float* dWih0 = (const float*)d_in[12];
  const float* dWhh0 = (const float*)d_in[13];
  const float* dbih0 = (const float*)d_in[14];
  const float* dbhh0 = (const float*)d_in[15];
  const float* dWih1 = (const float*)d_in[16];
  const float* dWhh1 = (const float*)d_in[17];
  const float* dbih1 = (const float*)d_in[18];
  const float* dbhh1 = (const float*)d_in[19];
  const float* outW  = (const float*)d_in[20];
  const float* outb  = (const float*)d_in[21];
  char* ws = (char*)d_ws;

  hipFuncSetAttribute(reinterpret_cast<const void*>(gru_persist),
                      hipFuncAttributeMaxDynamicSharedMemorySize, SMEM_BYTES);

  // zero: barrier counters/go + h0pack slot0 + encoder h1pack slot0
  hipMemsetAsync(ws, 0, OFF_H0P0 + HB, stream);
  hipMemsetAsync(ws + OFF_EH10, 0, HB, stream);

  prep_wf<<<3072, 256, 0, stream>>>(dWih0, dbih0, outW, outb, ws);
  gru_persist<<<256, 512, SMEM_BYTES, stream>>>(xe, xme, xd, xmd,
                                                eWih0, eWhh0, ebih0, ebhh0,
                                                eWih1, eWhh1, ebih1, ebhh1,
                                                dWih0, dWhh0, dbih0, dbhh0,
                                                dWih1, dWhh1, dbih1, dbhh1, ws);
  proj_kernel<<<NPRED * 7, 64, 0, stream>>>(ws, outW, outb, (float*)d_out);
}

// Round 6
// 5802.176 us; speedup vs baseline: 20.4793x; 1.0426x over previous
//
#include <hip/hip_runtime.h>
#include <math.h>

// GRU seq2seq on MI355X — Round 6: register-carried partial GEMMs + leaner barrier.
// Autoreg steady state: A(s) = Wf·h1(s-1) [+carryA] & produces carryB = gh1·h1(s-1);
//                       B(s) = gi1·h0(s) [+carryB] & produces carryA = gh0·h0(s).
// -> every autoreg interval reads ONE h buffer and runs 32 MFMAs (was 2 buffers).
// Encoder/label: fused 3-tile K-loop (h0 fragment loaded once for gh0+gi1).
// Barrier: two-level tree, pollers read the ROOT counter (go-store hop removed).

typedef _Float16 half8 __attribute__((ext_vector_type(8)));
typedef _Float16 half4f __attribute__((ext_vector_type(4)));
typedef float f32x4 __attribute__((ext_vector_type(4)));

#define DM    1024
#define TENC  192
#define TDEC  216
#define LBL   48
#define NPRED 168
#define HB    131072            // one packed h buffer: 1024*64*2 bytes
#define HE    65536             // elements per h buffer

// workspace byte offsets
// [0,4096): 32 leaf counters, 128B stride | 4096: root
#define OFF_H0P0 8192
#define OFF_EH10 (OFF_H0P0 + 2*HB)
#define OFF_DH1  (OFF_EH10 + 2*HB)
#define OFF_WF   (OFF_DH1 + 217*HB)
#define OFF_BF0  (OFF_WF + 3072*1024*2)

// LDS byte offsets (dynamic shared)
#define L_TA0 0                 // gh0 (Whh0)
#define L_TA1 32768             // Wf (dec only)
#define L_TB0 65536             // gi1 (Wih1)
#define L_TB1 98304             // gh1 (Whh1)
#define L_XW  131072            // xw[3][4][12] f32 = 576 B
#define L_BA  131648            // 16 f32
#define L_BAA 131712            // 16 f32
#define L_BB  131776            // 16 f32
#define L_TRA 131840            // 8 waves * 256 f32 = 8192 B
#define L_TRB 140032            // 8192 B
#define L_HSTA 148224           // 256 f16 = 512 B
#define L_HSTB 148736           // 512 B
#define SMEM_BYTES 149248

__device__ __forceinline__ float sigm(float x) { return 1.0f / (1.0f + __expf(-x)); }

// ---- device-coherent (LLC-level) accesses: bypass the non-coherent per-XCD L2.
__device__ __forceinline__ void coh_store64(void* p, unsigned long long v) {
  asm volatile("global_store_dwordx2 %0, %1, off sc0 sc1" :: "v"(p), "v"(v) : "memory");
}
__device__ __forceinline__ unsigned coh_load32(const void* p) {
  unsigned r;
  asm volatile("global_load_dword %0, %1, off sc0 sc1\n\ts_waitcnt vmcnt(0)"
               : "=v"(r) : "v"(p) : "memory");
  return r;
}

// ---- two-level grid barrier, poll-on-root. 256 blocks = 32 leaves x 8 blocks.
// Entry: drain coherent stores, s_barrier, tid0 arrives (relaxed adds: leaf then,
// if leaf-last, root). All tid0s poll the root for ep*32. Exit: one acquire-inv
// per block (L2 holds no dirty lines -> cheap), syncthreads.
__device__ __forceinline__ void gridbar(unsigned* leaf, unsigned* root,
                                        int tid, int bx, unsigned ep) {
  asm volatile("s_waitcnt vmcnt(0)" ::: "memory");
  __syncthreads();
  if (tid == 0) {
    unsigned old = __hip_atomic_fetch_add(&leaf[(bx >> 3) << 5], 1u,
                                          __ATOMIC_RELAXED, __HIP_MEMORY_SCOPE_AGENT);
    if (old == ep * 8u - 1u) {
      __hip_atomic_fetch_add(root, 1u, __ATOMIC_RELAXED, __HIP_MEMORY_SCOPE_AGENT);
    }
    while (coh_load32(root) < ep * 32u) __builtin_amdgcn_s_sleep(2);
    __builtin_amdgcn_fence(__ATOMIC_ACQUIRE, "agent");  // inv L1+L2
  }
  __syncthreads();
}

// ---- LDS tile fill: pack 16 rows (row map per 4-row gate group, -1 = zeros)
// into MFMA A-fragment order: elem((kb,quad,m),j) = ((kb*64 + quad*16 + m)*8 + j)
__device__ __forceinline__ void fill_tile_f32(char* smem, int off, const float* __restrict__ src,
                                              int u0, int g0, int g1, int g2, int g3, int tid) {
  const int w = tid >> 6, lane = tid & 63;
  int gsel[4] = {g0, g1, g2, g3};
#pragma unroll
  for (int mm = 0; mm < 2; ++mm) {
    const int m = w + mm * 8;
    const int g = gsel[m >> 2];
    const long srow = (g < 0) ? -1 : (long)g * DM + u0 + (m & 3);
#pragma unroll
    for (int p = 0; p < 4; ++p) {
      const int k = p * 256 + lane * 4;
      half4f hv;
      if (srow >= 0) {
        float4 v = *(const float4*)(src + srow * DM + k);
        hv = (half4f){(_Float16)v.x, (_Float16)v.y, (_Float16)v.z, (_Float16)v.w};
      } else {
        hv = (half4f){(_Float16)0.f, (_Float16)0.f, (_Float16)0.f, (_Float16)0.f};
      }
      const int kb = k >> 5, q = (k >> 3) & 3;
      const int elem = (kb * 64 + q * 16 + m) * 8 + (k & 7);
      *(half4f*)(smem + off + elem * 2) = hv;
    }
  }
}

__device__ __forceinline__ void fill_tile_f16(char* smem, int off, const _Float16* __restrict__ src,
                                              int u0, int g0, int g1, int g2, int g3, int tid) {
  const int w = tid >> 6, lane = tid & 63;
  int gsel[4] = {g0, g1, g2, g3};
#pragma unroll
  for (int mm = 0; mm < 2; ++mm) {
    const int m = w + mm * 8;
    const int g = gsel[m >> 2];
    const long srow = (g < 0) ? -1 : (long)g * DM + u0 + (m & 3);
#pragma unroll
    for (int p = 0; p < 4; ++p) {
      const int k = p * 256 + lane * 4;
      half4f hv;
      if (srow >= 0) hv = *(const half4f*)(src + srow * DM + k);
      else hv = (half4f){(_Float16)0.f, (_Float16)0.f, (_Float16)0.f, (_Float16)0.f};
      const int kb = k >> 5, q = (k >> 3) & 3;
      const int elem = (kb * 64 + q * 16 + m) * 8 + (k & 7);
      *(half4f*)(smem + off + elem * 2) = hv;
    }
  }
}

// small per-CU constants: x-side weight slice + fused biases
__device__ __forceinline__ void fill_small(char* smem, int u0, int tid,
    const float* __restrict__ Wih0, const float* __restrict__ bihA, const float* __restrict__ bhhA,
    const float* __restrict__ bih1, const float* __restrict__ bhh1, const float* __restrict__ bf0) {
  if (tid < 132) {
    const int rr = tid / 11, c = tid - rr * 11;
    const int g = rr >> 2, ul = rr & 3;
    ((float*)(smem + L_XW))[(g * 4 + ul) * 12 + c] = Wih0[(g * DM + u0 + ul) * 11 + c];
  }
  if (tid < 4) {
    const int u = u0 + tid;
    float* bA = (float*)(smem + L_BA);
    bA[tid] = bihA[u] + bhhA[u];
    bA[4 + tid] = bihA[DM + u] + bhhA[DM + u];
    bA[8 + tid] = bhhA[2 * DM + u];
    bA[12 + tid] = bihA[2 * DM + u];
    float* bB = (float*)(smem + L_BB);
    bB[tid] = bih1[u] + bhh1[u];
    bB[4 + tid] = bih1[DM + u] + bhh1[DM + u];
    bB[8 + tid] = bhh1[2 * DM + u];
    bB[12 + tid] = bih1[2 * DM + u];
    if (bf0) {
      float* bAa = (float*)(smem + L_BAA);
      bAa[tid] = bf0[u] + bhhA[u];
      bAa[4 + tid] = bf0[DM + u] + bhhA[DM + u];
      bAa[8 + tid] = bhhA[2 * DM + u];
      bAa[12 + tid] = bf0[2 * DM + u];
    }
  }
}

#define MFMA16 __builtin_amdgcn_mfma_f32_16x16x32_f16
#define ZERO4 ((f32x4){0.f, 0.f, 0.f, 0.f})

// ---- single-tile gemm: acc = T · src  (used at t==0 / d==0)
__device__ __forceinline__ f32x4 gemm1(const char* smem, int toff, const _Float16* __restrict__ bsrc,
                                       int kb0, int lane, int bs) {
  const half8* T = (const half8*)(smem + toff);
  const half8* Bp = (const half8*)bsrc + ((lane >> 4) << 6) + bs + (lane & 15);
  f32x4 a0 = ZERO4, a1 = ZERO4;
#pragma unroll 4
  for (int kb = kb0; kb < kb0 + 16; kb += 2) {
    half8 x0 = T[(kb << 6) + lane];
    half8 y0 = Bp[(size_t)kb << 8];
    half8 x1 = T[((kb + 1) << 6) + lane];
    half8 y1 = Bp[(size_t)(kb + 1) << 8];
    a0 = MFMA16(x0, y0, a0, 0, 0, 0);
    a1 = MFMA16(x1, y1, a1, 0, 0, 0);
  }
  return a0 + a1;
}

// ---- fused 3-tile gemm (merged encoder/label intervals + drains):
// outA = gh0·y0 ; outB = gi1·y0 + gh1·y1   (y0 from s0, y1 from s1)
__device__ __forceinline__ void gemm_fused3(const char* smem,
    const _Float16* __restrict__ s0, const _Float16* __restrict__ s1,
    int kb0, int lane, int bs, f32x4& outA, f32x4& outB) {
  const half8* TA  = (const half8*)(smem + L_TA0);
  const half8* TBi = (const half8*)(smem + L_TB0);
  const half8* TBh = (const half8*)(smem + L_TB1);
  const int bidx = ((lane >> 4) << 6) + bs + (lane & 15);
  const half8* B0 = (const half8*)s0 + bidx;
  const half8* B1 = (const half8*)s1 + bidx;
  f32x4 aE = ZERO4, aO = ZERO4, iE = ZERO4, iO = ZERO4, hE = ZERO4, hO = ZERO4;
#pragma unroll 2
  for (int kb = kb0; kb < kb0 + 16; kb += 2) {
    half8 y0a = B0[(size_t)kb << 8];
    half8 y1a = B1[(size_t)kb << 8];
    half8 y0b = B0[(size_t)(kb + 1) << 8];
    half8 y1b = B1[(size_t)(kb + 1) << 8];
    aE = MFMA16(TA[(kb << 6) + lane], y0a, aE, 0, 0, 0);
    iE = MFMA16(TBi[(kb << 6) + lane], y0a, iE, 0, 0, 0);
    hE = MFMA16(TBh[(kb << 6) + lane], y1a, hE, 0, 0, 0);
    aO = MFMA16(TA[((kb + 1) << 6) + lane], y0b, aO, 0, 0, 0);
    iO = MFMA16(TBi[((kb + 1) << 6) + lane], y0b, iO, 0, 0, 0);
    hO = MFMA16(TBh[((kb + 1) << 6) + lane], y1b, hO, 0, 0, 0);
  }
  outA = aE + aO;
  outB = (iE + iO) + (hE + hO);
}

// ---- autoreg A-interval: reads dh1[s] only.
// outA = carryA + Wf·y1 ; outCB = gh1·y1
__device__ __forceinline__ void gemm_A_auto(const char* smem, const _Float16* __restrict__ s1,
    int kb0, int lane, int bs, f32x4 carryA, f32x4& outA, f32x4& outCB) {
  const half8* TWf = (const half8*)(smem + L_TA1);
  const half8* TBh = (const half8*)(smem + L_TB1);
  const int bidx = ((lane >> 4) << 6) + bs + (lane & 15);
  const half8* B1 = (const half8*)s1 + bidx;
  f32x4 aE = carryA, aO = ZERO4, cE = ZERO4, cO = ZERO4;
#pragma unroll 4
  for (int kb = kb0; kb < kb0 + 16; kb += 2) {
    half8 y1a = B1[(size_t)kb << 8];
    half8 y1b = B1[(size_t)(kb + 1) << 8];
    aE = MFMA16(TWf[(kb << 6) + lane], y1a, aE, 0, 0, 0);
    cE = MFMA16(TBh[(kb << 6) + lane], y1a, cE, 0, 0, 0);
    aO = MFMA16(TWf[((kb + 1) << 6) + lane], y1b, aO, 0, 0, 0);
    cO = MFMA16(TBh[((kb + 1) << 6) + lane], y1b, cO, 0, 0, 0);
  }
  outA = aE + aO;
  outCB = cE + cO;
}

// ---- autoreg B-interval: reads h0-new only.
// outB = carryB + gi1·y0 ; outCA = gh0·y0 (carry for next A)
__device__ __forceinline__ void gemm_B_auto(const char* smem, const _Float16* __restrict__ s0,
    int kb0, int lane, int bs, f32x4 carryB, f32x4& outB, f32x4& outCA) {
  const half8* TBi = (const half8*)(smem + L_TB0);
  const half8* TA  = (const half8*)(smem + L_TA0);
  const int bidx = ((lane >> 4) << 6) + bs + (lane & 15);
  const half8* B0 = (const half8*)s0 + bidx;
  f32x4 bE = carryB, bO = ZERO4, cE = ZERO4, cO = ZERO4;
#pragma unroll 4
  for (int kb = kb0; kb < kb0 + 16; kb += 2) {
    half8 y0a = B0[(size_t)kb << 8];
    half8 y0b = B0[(size_t)(kb + 1) << 8];
    bE = MFMA16(TBi[(kb << 6) + lane], y0a, bE, 0, 0, 0);
    cE = MFMA16(TA[(kb << 6) + lane], y0a, cE, 0, 0, 0);
    bO = MFMA16(TBi[((kb + 1) << 6) + lane], y0b, bO, 0, 0, 0);
    cO = MFMA16(TA[((kb + 1) << 6) + lane], y0b, cO, 0, 0, 0);
  }
  outB = bE + bO;
  outCA = cE + cO;
}

// ---- write acc to a TR region (all 8 waves)
__device__ __forceinline__ void tr_store(char* smem, int trOff, int w, int lane, f32x4 acc) {
  float* tr = (float*)(smem + trOff) + (w << 8);
  const int quad = lane >> 4, col = lane & 15;
  tr[(quad * 4 + 0) * 16 + col] = acc[0];
  tr[(quad * 4 + 1) * 16 + col] = acc[1];
  tr[(quad * 4 + 2) * 16 + col] = acc[2];
  tr[(quad * 4 + 3) * 16 + col] = acc[3];
}

// ---- x-side GEMV precompute. xmode 1: 7 inputs + 4 marks; 2: marks only.
__device__ __forceinline__ void x_pre(const char* smem, int xmode,
    const float* __restrict__ xin, const float* __restrict__ xmk,
    int t, int seqT, int b, int ul, float& xr, float& xz, float& xn) {
  const float* xw = (const float*)(smem + L_XW);
  xr = 0.f; xz = 0.f; xn = 0.f;
  if (xmode == 1) {
    const float* xp = xin + (size_t)(b * seqT + t) * 7;
#pragma unroll
    for (int c = 0; c < 7; ++c) {
      float v = xp[c];
      xr = fmaf(xw[ul * 12 + c], v, xr);
      xz = fmaf(xw[(4 + ul) * 12 + c], v, xz);
      xn = fmaf(xw[(8 + ul) * 12 + c], v, xn);
    }
  }
  const float* mp = xmk + (size_t)(b * seqT + t) * 4;
#pragma unroll
  for (int m = 0; m < 4; ++m) {
    float v = mp[m];
    xr = fmaf(xw[ul * 12 + 7 + m], v, xr);
    xz = fmaf(xw[(4 + ul) * 12 + 7 + m], v, xz);
    xn = fmaf(xw[(8 + ul) * 12 + 7 + m], v, xn);
  }
}

// ---- gate epilogue for one wave group (wb=0: waves0-3, wb=4: waves4-7).
__device__ __forceinline__ void epi(char* smem, int trOff, int stOff, int wb,
                                    int biasOff, float pxr, float pxz, float pxn,
                                    int tid, float& hprev) {
  const int lane = tid & 63, w = tid >> 6;
  const int bg = w - wb;
  const int col = lane & 15, ul = lane >> 4;
  const float* t0 = (const float*)(smem + trOff) + (bg << 8);
  const float* t1 = t0 + (4 << 8);
  const int b = (bg << 4) + col;
  float vr  = t0[ul * 16 + col]        + t1[ul * 16 + col];
  float vz  = t0[(4 + ul) * 16 + col]  + t1[(4 + ul) * 16 + col];
  float vnh = t0[(8 + ul) * 16 + col]  + t1[(8 + ul) * 16 + col];
  float vni = t0[(12 + ul) * 16 + col] + t1[(12 + ul) * 16 + col];
  const float* bias = (const float*)(smem + biasOff);
  float rg = sigm(vr + bias[ul] + pxr);
  float zg = sigm(vz + bias[4 + ul] + pxz);
  float ng = tanhf((vni + bias[12 + ul] + pxn) + rg * (vnh + bias[8 + ul]));
  float hn = ng + zg * (hprev - ng);
  hprev = hn;
  ((_Float16*)(smem + stOff))[b * 4 + ul] = (_Float16)hn;
}

// ---- coherent 8B store of a 512B stage region (one wave: i = 0..63)
__device__ __forceinline__ void st8(_Float16* dst, int u0, int i, const char* stage) {
  unsigned long long v = *(const unsigned long long*)(stage + i * 8);
  char* gp = (char*)dst + (((size_t)(u0 >> 3)) * 64 + i) * 16 + (size_t)(u0 & 7) * 2;
  coh_store64(gp, v);
}

// ---- prep: Wf = dW_ih0[:, :7] @ out_W (f16), bf0 = db_ih0 + dW_ih0[:, :7] @ out_b
__global__ __launch_bounds__(256) void prep_wf(const float* __restrict__ dWih0,
                                               const float* __restrict__ dbih0,
                                               const float* __restrict__ outW,
                                               const float* __restrict__ outb,
                                               char* __restrict__ ws) {
  const int j = blockIdx.x;
  _Float16* wf = (_Float16*)(ws + OFF_WF);
  float* bf0 = (float*)(ws + OFF_BF0);
  float wrow[7];
#pragma unroll
  for (int c = 0; c < 7; ++c) wrow[c] = dWih0[j * 11 + c];
#pragma unroll
  for (int p = 0; p < 4; ++p) {
    const int k = p * 256 + threadIdx.x;
    float acc = 0.f;
#pragma unroll
    for (int c = 0; c < 7; ++c) acc = fmaf(wrow[c], outW[c * DM + k], acc);
    wf[(size_t)j * DM + k] = (_Float16)acc;
  }
  if (threadIdx.x == 0) {
    float bb = dbih0[j];
#pragma unroll
    for (int c = 0; c < 7; ++c) bb = fmaf(wrow[c], outb[c], bb);
    bf0[j] = bb;
  }
}

__global__ __launch_bounds__(512) void gru_persist(
    const float* __restrict__ xe,  const float* __restrict__ xme,
    const float* __restrict__ xd,  const float* __restrict__ xmd,
    const float* __restrict__ eWih0, const float* __restrict__ eWhh0,
    const float* __restrict__ ebih0, const float* __restrict__ ebhh0,
    const float* __restrict__ eWih1, const float* __restrict__ eWhh1,
    const float* __restrict__ ebih1, const float* __restrict__ ebhh1,
    const float* __restrict__ dWih0, const float* __restrict__ dWhh0,
    const float* __restrict__ dbih0, const float* __restrict__ dbhh0,
    const float* __restrict__ dWih1, const float* __restrict__ dWhh1,
    const float* __restrict__ dbih1, const float* __restrict__ dbhh1,
    char* __restrict__ ws) {
  extern __shared__ char smem[];
  const int tid = threadIdx.x, bx = blockIdx.x;
  const int lane = tid & 63;
  const int w = tid >> 6;
  const int bg = w & 3, kslice = w >> 2;
  const int bs = bg << 4, kb0 = kslice << 4;
  const int u0 = bx << 2;
  const int bA = ((w & 3) << 4) + (lane & 15);   // epilogue batch coord
  const int ulA = lane >> 4;                      // epilogue unit coord

  unsigned* leaf = (unsigned*)ws;
  unsigned* root = (unsigned*)(ws + 4096);
  _Float16* h0p[2] = {(_Float16*)(ws + OFF_H0P0), (_Float16*)(ws + OFF_H0P0 + HB)};
  _Float16* eh1[2] = {(_Float16*)(ws + OFF_EH10), (_Float16*)(ws + OFF_EH10 + HB)};
  _Float16* dh1 = (_Float16*)(ws + OFF_DH1);
  const _Float16* wf = (const _Float16*)(ws + OFF_WF);
  const float* bf0 = (const float*)(ws + OFF_BF0);

  float hA = 0.f, hB = 0.f;
  unsigned ep = 0;

  // ---------- encoder weights -> LDS ----------
  fill_tile_f32(smem, L_TA0, eWhh0, u0, 0, 1, 2, -1, tid);   // gh0: r,z,nh | zeros
  fill_tile_f32(smem, L_TB0, eWih1, u0, 0, 1, -1, 2, tid);   // gi1: r,z | zeros | ni
  fill_tile_f32(smem, L_TB1, eWhh1, u0, 0, 1, 2, -1, tid);   // gh1: r,z,nh | zeros
  fill_small(smem, u0, tid, eWih0, ebih0, ebhh0, ebih1, ebhh1, nullptr);
  __syncthreads();

  // ---------- encoder: merged intervals t = 0..191: L0(t) + L1(t-1) ----------
  for (int t = 0; t < TENC; ++t) {
    const int r = t & 1;
    float pxr, pxz, pxn;
    if (w < 4) x_pre(smem, 1, xe, xme, t, TENC, bA, ulA, pxr, pxz, pxn);
    f32x4 aA, aB;
    if (t > 0) gemm_fused3(smem, h0p[r], eh1[(t - 1) & 1], kb0, lane, bs, aA, aB);
    else       aA = gemm1(smem, L_TA0, h0p[r], kb0, lane, bs);
    tr_store(smem, L_TRA, w, lane, aA);
    if (t > 0) tr_store(smem, L_TRB, w, lane, aB);
    __syncthreads();
    if (w < 4) epi(smem, L_TRA, L_HSTA, 0, L_BA, pxr, pxz, pxn, tid, hA);
    else if (t > 0) epi(smem, L_TRB, L_HSTB, 4, L_BB, 0.f, 0.f, 0.f, tid, hB);
    __syncthreads();
    if (tid < 64) st8(h0p[r ^ 1], u0, tid, smem + L_HSTA);
    else if (t > 0 && tid < 128) st8(eh1[t & 1], u0, tid - 64, smem + L_HSTB);
    gridbar(leaf, root, tid, bx, ++ep);
  }
  // drain: L1e(191) -> dh1[0]  (h0e(191) in h0p[0]; h1e(190) in eh1[1])
  {
    f32x4 aA, aB;
    gemm_fused3(smem, h0p[0], eh1[1], kb0, lane, bs, aA, aB);  // aA discarded
    tr_store(smem, L_TRB, w, lane, aB);
    __syncthreads();
    if (w >= 4) epi(smem, L_TRB, L_HSTB, 4, L_BB, 0.f, 0.f, 0.f, tid, hB);
    __syncthreads();
    if (tid >= 64 && tid < 128) st8(dh1, u0, tid - 64, smem + L_HSTB);
    gridbar(leaf, root, tid, bx, ++ep);
  }

  // ---------- decoder weights -> LDS ----------
  fill_tile_f32(smem, L_TA0, dWhh0, u0, 0, 1, 2, -1, tid);
  fill_tile_f16(smem, L_TA1, wf,    u0, 0, 1, -1, 2, tid);   // Wf: r,z | zeros | ni
  fill_tile_f32(smem, L_TB0, dWih1, u0, 0, 1, -1, 2, tid);
  fill_tile_f32(smem, L_TB1, dWhh1, u0, 0, 1, 2, -1, tid);
  fill_small(smem, u0, tid, dWih0, dbih0, dbhh0, dbih1, dbhh1, bf0);
  __syncthreads();

  // ---------- label region: merged intervals d = 0..47: L0d(d) + L1d(d-1) ----------
  for (int d = 0; d < LBL; ++d) {
    const int r = d & 1;
    float pxr, pxz, pxn;
    if (w < 4) x_pre(smem, 1, xd, xmd, d, TDEC, bA, ulA, pxr, pxz, pxn);
    f32x4 aA, aB;
    if (d > 0) gemm_fused3(smem, h0p[r], dh1 + (size_t)(d - 1) * HE, kb0, lane, bs, aA, aB);
    else       aA = gemm1(smem, L_TA0, h0p[r], kb0, lane, bs);
    tr_store(smem, L_TRA, w, lane, aA);
    if (d > 0) tr_store(smem, L_TRB, w, lane, aB);
    __syncthreads();
    if (w < 4) epi(smem, L_TRA, L_HSTA, 0, L_BA, pxr, pxz, pxn, tid, hA);
    else if (d > 0) epi(smem, L_TRB, L_HSTB, 4, L_BB, 0.f, 0.f, 0.f, tid, hB);
    __syncthreads();
    if (tid < 64) st8(h0p[r ^ 1], u0, tid, smem + L_HSTA);
    else if (d > 0 && tid < 128) st8(dh1 + (size_t)d * HE, u0, tid - 64, smem + L_HSTB);
    gridbar(leaf, root, tid, bx, ++ep);
  }
  // drain: L1d(47) -> dh1[48], and seed carryA = gh0·h0d(47) for A(48)
  f32x4 carryA, carryB;
  {
    f32x4 aB;
    gemm_fused3(smem, h0p[0], dh1 + (size_t)47 * HE, kb0, lane, bs, carryA, aB);
    tr_store(smem, L_TRB, w, lane, aB);
    __syncthreads();
    if (w >= 4) epi(smem, L_TRB, L_HSTB, 4, L_BB, 0.f, 0.f, 0.f, tid, hB);
    __syncthreads();
    if (tid >= 64 && tid < 128) st8(dh1 + (size_t)48 * HE, u0, tid - 64, smem + L_HSTB);
    gridbar(leaf, root, tid, bx, ++ep);
  }

  // ---------- autoregressive region: s = 48..215, 2 single-buffer intervals/step ----------
  for (int s = LBL; s < TDEC; ++s) {
    const int r = s & 1;
    // A(s): h0(s) from [carryA = gh0·h0(s-1)] + Wf·h1(s-1) + marks; carryB = gh1·h1(s-1)
    {
      float pxr, pxz, pxn;
      if (w < 4) x_pre(smem, 2, nullptr, xmd, s, TDEC, bA, ulA, pxr, pxz, pxn);
      f32x4 aA;
      gemm_A_auto(smem, dh1 + (size_t)s * HE, kb0, lane, bs, carryA, aA, carryB);
      tr_store(smem, L_TRA, w, lane, aA);
      __syncthreads();
      if (w < 4) epi(smem, L_TRA, L_HSTA, 0, L_BAA, pxr, pxz, pxn, tid, hA);
      __syncthreads();
      if (tid < 64) st8(h0p[r ^ 1], u0, tid, smem + L_HSTA);
      gridbar(leaf, root, tid, bx, ++ep);
    }
    // B(s): h1(s) from [carryB] + gi1·h0(s); carryA = gh0·h0(s) for A(s+1)
    {
      f32x4 aB;
      gemm_B_auto(smem, h0p[r ^ 1], kb0, lane, bs, carryB, aB, carryA);
      tr_store(smem, L_TRB, w, lane, aB);
      __syncthreads();
      if (w >= 4) epi(smem, L_TRB, L_HSTB, 4, L_BB, 0.f, 0.f, 0.f, tid, hB);
      __syncthreads();
      if (tid >= 64 && tid < 128) st8(dh1 + (size_t)(s + 1) * HE, u0, tid - 64, smem + L_HSTB);
      gridbar(leaf, root, tid, bx, ++ep);
    }
  }
}

// ---- epilogue projection: preds from stored h1 history (packed f16)
__global__ __launch_bounds__(64) void proj_kernel(const char* __restrict__ ws,
                                                  const float* __restrict__ outW,
                                                  const float* __restrict__ outb,
                                                  float* __restrict__ out) {
  const int ti = blockIdx.x / 7, c = blockIdx.x % 7;
  const _Float16* h = (const _Float16*)(ws + OFF_DH1) + (size_t)(LBL + 1 + ti) * HE;
  const int b = threadIdx.x;
  const float* wrow = outW + c * DM;
  float acc = outb[c];
#pragma unroll 4
  for (int k8 = 0; k8 < 128; ++k8) {
    const half8 hv = *(const half8*)(h + ((size_t)k8 * 64 + b) * 8);
    const float* wp = wrow + k8 * 8;
#pragma unroll
    for (int j = 0; j < 8; ++j) acc = fmaf((float)hv[j], wp[j], acc);
  }
  out[(size_t)b * (NPRED * 7) + ti * 7 + c] = acc;
}

extern "C" void kernel_launch(void* const* d_in, const int* in_sizes, int n_in,
                              void* d_out, int out_size, void* d_ws, size_t ws_size,
                              hipStream_t stream) {
  (void)in_sizes; (void)n_in; (void)out_size; (void)ws_size;
  const float* xe    = (const float*)d_in[0];
  const float* xme   = (const float*)d_in[1];
  const float* xd    = (const float*)d_in[2];
  const float* xmd   = (const float*)d_in[3];
  const float* eWih0 = (const float*)d_in[4];
  const float* eWhh0 = (const float*)d_in[5];
  const float* ebih0 = (const float*)d_in[6];
  const float* ebhh0 = (const float*)d_in[7];
  const float* eWih1 = (const float*)d_in[8];
  const float* eWhh1 = (const float*)d_in[9];
  const float* ebih1 = (const float*)d_in[10];
  const float* ebhh1 = (const float*)d_in[11];
  const float* dWih0 = (const float*)d_in[12];
  const float* dWhh0 = (const float*)d_in[13];
  const float* dbih0 = (const float*)d_in[14];
  const float* dbhh0 = (const float*)d_in[15];
  const float* dWih1 = (const float*)d_in[16];
  const float* dWhh1 = (const float*)d_in[17];
  const float* dbih1 = (const float*)d_in[18];
  const float* dbhh1 = (const float*)d_in[19];
  const float* outW  = (const float*)d_in[20];
  const float* outb  = (const float*)d_in[21];
  char* ws = (char*)d_ws;

  hipFuncSetAttribute(reinterpret_cast<const void*>(gru_persist),
                      hipFuncAttributeMaxDynamicSharedMemorySize, SMEM_BYTES);

  // zero: barrier counters + h0pack slot0 + encoder h1pack slot0
  hipMemsetAsync(ws, 0, OFF_H0P0 + HB, stream);
  hipMemsetAsync(ws + OFF_EH10, 0, HB, stream);

  prep_wf<<<3072, 256, 0, stream>>>(dWih0, dbih0, outW, outb, ws);
  gru_persist<<<256, 512, SMEM_BYTES, stream>>>(xe, xme, xd, xmd,
                                                eWih0, eWhh0, ebih0, ebhh0,
                                                eWih1, eWhh1, ebih1, ebhh1,
                                                dWih0, dWhh0, dbih0, dbhh0,
                                                dWih1, dWhh1, dbih1, dbhh1, ws);
  proj_kernel<<<NPRED * 7, 64, 0, stream>>>(ws, outW, outb, (float*)d_out);
}

// Round 7
// 3087.758 us; speedup vs baseline: 38.4825x; 1.8791x over previous
//
#include <hip/hip_runtime.h>
#include <math.h>

// GRU seq2seq on MI355X — Round 7: split-phase barrier + inv-free coherence.
// - bar_arrive / bar_wait split: carry-GEMMs (register operands) + x_pre run
//   between arrive and wait, hiding barrier latency.
// - NO acquire-inv: all h traffic via sc0 sc1 asm (write-through LLC stores,
//   LLC-direct loads). Read-only x/bias stay cache-warm across intervals.
// - Encoder/label: lag-2 layer pipeline; interval t computes L0(t) + L1(t-2),
//   post-arrive carryI = gi1*h0(t-1) from register-held y0.
// - Autoreg: A/B intervals with register carries (R6 scheme) + split barrier.
// Epochs: 192+2 (enc+drains) + 48+2 (label+drains) + 336 (autoreg) = 580.

typedef _Float16 half8 __attribute__((ext_vector_type(8)));
typedef _Float16 half4f __attribute__((ext_vector_type(4)));
typedef float f32x4 __attribute__((ext_vector_type(4)));

#define DM    1024
#define TENC  192
#define TDEC  216
#define LBL   48
#define NPRED 168
#define HB    131072            // one packed h buffer: 1024*64*2 bytes
#define HE    65536             // elements per h buffer

// workspace byte offsets
// [0,4096): 32 leaf counters, 128B stride | 4096: root
#define OFF_H0P0 8192
#define OFF_EH10 (OFF_H0P0 + 2*HB)
#define OFF_DH1  (OFF_EH10 + 2*HB)
#define OFF_WF   (OFF_DH1 + 217*HB)
#define OFF_BF0  (OFF_WF + 3072*1024*2)

// LDS byte offsets (dynamic shared)
#define L_TA0 0                 // gh0 (Whh0)
#define L_TA1 32768             // Wf (dec only)
#define L_TB0 65536             // gi1 (Wih1)
#define L_TB1 98304             // gh1 (Whh1)
#define L_XW  131072            // xw[3][4][12] f32 = 576 B
#define L_BA  131648            // 16 f32
#define L_BAA 131712            // 16 f32
#define L_BB  131776            // 16 f32
#define L_TRA 131840            // 8 waves * 256 f32 = 8192 B
#define L_TRB 140032            // 8192 B
#define L_HSTA 148224           // 256 f16 = 512 B
#define L_HSTB 148736           // 512 B
#define SMEM_BYTES 149248

__device__ __forceinline__ float sigm(float x) { return 1.0f / (1.0f + __expf(-x)); }

// ---- device-coherent (LLC-level) accesses: bypass the non-coherent per-XCD L2.
__device__ __forceinline__ void coh_store64(void* p, unsigned long long v) {
  asm volatile("global_store_dwordx2 %0, %1, off sc0 sc1" :: "v"(p), "v"(v) : "memory");
}
__device__ __forceinline__ unsigned coh_load32(const void* p) {
  unsigned r;
  asm volatile("global_load_dword %0, %1, off sc0 sc1\n\ts_waitcnt vmcnt(0)"
               : "=v"(r) : "v"(p) : "memory");
  return r;
}
__device__ __forceinline__ half8 coh_load_h8(const void* p) {
  half8 r;
  asm volatile("global_load_dwordx4 %0, %1, off sc0 sc1" : "=v"(r) : "v"(p));
  return r;
}
// drain all outstanding vmem; ties the 16 y-frags so dependent MFMAs can't hoist
__device__ __forceinline__ void ysync16(half8* y) {
  asm volatile("s_waitcnt vmcnt(0)"
               : "+v"(y[0]), "+v"(y[1]), "+v"(y[2]), "+v"(y[3]),
                 "+v"(y[4]), "+v"(y[5]), "+v"(y[6]), "+v"(y[7]),
                 "+v"(y[8]), "+v"(y[9]), "+v"(y[10]), "+v"(y[11]),
                 "+v"(y[12]), "+v"(y[13]), "+v"(y[14]), "+v"(y[15])
               :: "memory");
}

// ---- split-phase two-level grid barrier. 256 blocks = 32 leaves x 8 blocks.
__device__ __forceinline__ void bar_arrive(unsigned* leaf, unsigned* root,
                                           int tid, int bx, unsigned ep) {
  asm volatile("s_waitcnt vmcnt(0)" ::: "memory");   // drain our coherent stores
  __syncthreads();
  if (tid == 0) {
    unsigned old = __hip_atomic_fetch_add(&leaf[(bx >> 3) << 5], 1u,
                                          __ATOMIC_RELAXED, __HIP_MEMORY_SCOPE_AGENT);
    if (old == ep * 8u - 1u)
      __hip_atomic_fetch_add(root, 1u, __ATOMIC_RELAXED, __HIP_MEMORY_SCOPE_AGENT);
  }
}
__device__ __forceinline__ void bar_wait(unsigned* root, int tid, unsigned ep) {
  if (tid == 0) {
    while (coh_load32(root) < ep * 32u) __builtin_amdgcn_s_sleep(1);
  }
  __syncthreads();
}

// ---- LDS tile fill: pack 16 rows (row map per 4-row gate group, -1 = zeros)
// into MFMA A-fragment order: elem((kb,quad,m),j) = ((kb*64 + quad*16 + m)*8 + j)
__device__ __forceinline__ void fill_tile_f32(char* smem, int off, const float* __restrict__ src,
                                              int u0, int g0, int g1, int g2, int g3, int tid) {
  const int w = tid >> 6, lane = tid & 63;
  int gsel[4] = {g0, g1, g2, g3};
#pragma unroll
  for (int mm = 0; mm < 2; ++mm) {
    const int m = w + mm * 8;
    const int g = gsel[m >> 2];
    const long srow = (g < 0) ? -1 : (long)g * DM + u0 + (m & 3);
#pragma unroll
    for (int p = 0; p < 4; ++p) {
      const int k = p * 256 + lane * 4;
      half4f hv;
      if (srow >= 0) {
        float4 v = *(const float4*)(src + srow * DM + k);
        hv = (half4f){(_Float16)v.x, (_Float16)v.y, (_Float16)v.z, (_Float16)v.w};
      } else {
        hv = (half4f){(_Float16)0.f, (_Float16)0.f, (_Float16)0.f, (_Float16)0.f};
      }
      const int kb = k >> 5, q = (k >> 3) & 3;
      const int elem = (kb * 64 + q * 16 + m) * 8 + (k & 7);
      *(half4f*)(smem + off + elem * 2) = hv;
    }
  }
}

__device__ __forceinline__ void fill_tile_f16(char* smem, int off, const _Float16* __restrict__ src,
                                              int u0, int g0, int g1, int g2, int g3, int tid) {
  const int w = tid >> 6, lane = tid & 63;
  int gsel[4] = {g0, g1, g2, g3};
#pragma unroll
  for (int mm = 0; mm < 2; ++mm) {
    const int m = w + mm * 8;
    const int g = gsel[m >> 2];
    const long srow = (g < 0) ? -1 : (long)g * DM + u0 + (m & 3);
#pragma unroll
    for (int p = 0; p < 4; ++p) {
      const int k = p * 256 + lane * 4;
      half4f hv;
      if (srow >= 0) hv = *(const half4f*)(src + srow * DM + k);
      else hv = (half4f){(_Float16)0.f, (_Float16)0.f, (_Float16)0.f, (_Float16)0.f};
      const int kb = k >> 5, q = (k >> 3) & 3;
      const int elem = (kb * 64 + q * 16 + m) * 8 + (k & 7);
      *(half4f*)(smem + off + elem * 2) = hv;
    }
  }
}

// small per-CU constants: x-side weight slice + fused biases
__device__ __forceinline__ void fill_small(char* smem, int u0, int tid,
    const float* __restrict__ Wih0, const float* __restrict__ bihA, const float* __restrict__ bhhA,
    const float* __restrict__ bih1, const float* __restrict__ bhh1, const float* __restrict__ bf0) {
  if (tid < 132) {
    const int rr = tid / 11, c = tid - rr * 11;
    const int g = rr >> 2, ul = rr & 3;
    ((float*)(smem + L_XW))[(g * 4 + ul) * 12 + c] = Wih0[(g * DM + u0 + ul) * 11 + c];
  }
  if (tid < 4) {
    const int u = u0 + tid;
    float* bA = (float*)(smem + L_BA);
    bA[tid] = bihA[u] + bhhA[u];
    bA[4 + tid] = bihA[DM + u] + bhhA[DM + u];
    bA[8 + tid] = bhhA[2 * DM + u];
    bA[12 + tid] = bihA[2 * DM + u];
    float* bB = (float*)(smem + L_BB);
    bB[tid] = bih1[u] + bhh1[u];
    bB[4 + tid] = bih1[DM + u] + bhh1[DM + u];
    bB[8 + tid] = bhh1[2 * DM + u];
    bB[12 + tid] = bih1[2 * DM + u];
    if (bf0) {
      float* bAa = (float*)(smem + L_BAA);
      bAa[tid] = bf0[u] + bhhA[u];
      bAa[4 + tid] = bf0[DM + u] + bhhA[DM + u];
      bAa[8 + tid] = bhhA[2 * DM + u];
      bAa[12 + tid] = bf0[2 * DM + u];
    }
  }
}

#define MFMA16 __builtin_amdgcn_mfma_f32_16x16x32_f16
#define ZERO4 ((f32x4){0.f, 0.f, 0.f, 0.f})

// ---- batch-issue 16 coherent y-fragment loads for this wave's (bs, kb0)
__device__ __forceinline__ void yload(half8* y, const _Float16* src, int kb0, int lane, int bs) {
  const half8* B = (const half8*)src + ((lane >> 4) << 6) + bs + (lane & 15);
#pragma unroll
  for (int i = 0; i < 16; ++i)
    y[i] = coh_load_h8(B + ((size_t)(kb0 + i) << 8));
}

// ---- 16-MFMA pass of one LDS tile against register-held y-frags
__device__ __forceinline__ f32x4 gemm_reg(const char* smem, int toff, int kb0, int lane,
                                          const half8* y, f32x4 seed) {
  const half8* T = (const half8*)(smem + toff);
  f32x4 aE = seed, aO = ZERO4;
#pragma unroll
  for (int i = 0; i < 16; i += 2) {
    aE = MFMA16(T[((kb0 + i) << 6) + lane], y[i], aE, 0, 0, 0);
    aO = MFMA16(T[((kb0 + i + 1) << 6) + lane], y[i + 1], aO, 0, 0, 0);
  }
  return aE + aO;
}

// ---- write acc to a TR region (all 8 waves)
__device__ __forceinline__ void tr_store(char* smem, int trOff, int w, int lane, f32x4 acc) {
  float* tr = (float*)(smem + trOff) + (w << 8);
  const int quad = lane >> 4, col = lane & 15;
  tr[(quad * 4 + 0) * 16 + col] = acc[0];
  tr[(quad * 4 + 1) * 16 + col] = acc[1];
  tr[(quad * 4 + 2) * 16 + col] = acc[2];
  tr[(quad * 4 + 3) * 16 + col] = acc[3];
}

// ---- x-side GEMV precompute. xmode 1: 7 inputs + 4 marks; 2: marks only.
__device__ __forceinline__ void x_pre(const char* smem, int xmode,
    const float* __restrict__ xin, const float* __restrict__ xmk,
    int t, int seqT, int b, int ul, float& xr, float& xz, float& xn) {
  const float* xw = (const float*)(smem + L_XW);
  xr = 0.f; xz = 0.f; xn = 0.f;
  if (xmode == 1) {
    const float* xp = xin + (size_t)(b * seqT + t) * 7;
#pragma unroll
    for (int c = 0; c < 7; ++c) {
      float v = xp[c];
      xr = fmaf(xw[ul * 12 + c], v, xr);
      xz = fmaf(xw[(4 + ul) * 12 + c], v, xz);
      xn = fmaf(xw[(8 + ul) * 12 + c], v, xn);
    }
  }
  const float* mp = xmk + (size_t)(b * seqT + t) * 4;
#pragma unroll
  for (int m = 0; m < 4; ++m) {
    float v = mp[m];
    xr = fmaf(xw[ul * 12 + 7 + m], v, xr);
    xz = fmaf(xw[(4 + ul) * 12 + 7 + m], v, xz);
    xn = fmaf(xw[(8 + ul) * 12 + 7 + m], v, xn);
  }
}

// ---- gate epilogue for one wave group (wb=0: waves0-3, wb=4: waves4-7).
__device__ __forceinline__ void epi(char* smem, int trOff, int stOff, int wb,
                                    int biasOff, float pxr, float pxz, float pxn,
                                    int tid, float& hprev) {
  const int lane = tid & 63, w = tid >> 6;
  const int bg = w - wb;
  const int col = lane & 15, ul = lane >> 4;
  const float* t0 = (const float*)(smem + trOff) + (bg << 8);
  const float* t1 = t0 + (4 << 8);
  const int b = (bg << 4) + col;
  float vr  = t0[ul * 16 + col]        + t1[ul * 16 + col];
  float vz  = t0[(4 + ul) * 16 + col]  + t1[(4 + ul) * 16 + col];
  float vnh = t0[(8 + ul) * 16 + col]  + t1[(8 + ul) * 16 + col];
  float vni = t0[(12 + ul) * 16 + col] + t1[(12 + ul) * 16 + col];
  const float* bias = (const float*)(smem + biasOff);
  float rg = sigm(vr + bias[ul] + pxr);
  float zg = sigm(vz + bias[4 + ul] + pxz);
  float ng = tanhf((vni + bias[12 + ul] + pxn) + rg * (vnh + bias[8 + ul]));
  float hn = ng + zg * (hprev - ng);
  hprev = hn;
  ((_Float16*)(smem + stOff))[b * 4 + ul] = (_Float16)hn;
}

// ---- coherent 8B store of a 512B stage region (one wave: i = 0..63)
__device__ __forceinline__ void st8(_Float16* dst, int u0, int i, const char* stage) {
  unsigned long long v = *(const unsigned long long*)(stage + i * 8);
  char* gp = (char*)dst + (((size_t)(u0 >> 3)) * 64 + i) * 16 + (size_t)(u0 & 7) * 2;
  coh_store64(gp, v);
}

// ---- prep: Wf = dW_ih0[:, :7] @ out_W (f16), bf0 = db_ih0 + dW_ih0[:, :7] @ out_b
__global__ __launch_bounds__(256) void prep_wf(const float* __restrict__ dWih0,
                                               const float* __restrict__ dbih0,
                                               const float* __restrict__ outW,
                                               const float* __restrict__ outb,
                                               char* __restrict__ ws) {
  const int j = blockIdx.x;
  _Float16* wf = (_Float16*)(ws + OFF_WF);
  float* bf0 = (float*)(ws + OFF_BF0);
  float wrow[7];
#pragma unroll
  for (int c = 0; c < 7; ++c) wrow[c] = dWih0[j * 11 + c];
#pragma unroll
  for (int p = 0; p < 4; ++p) {
    const int k = p * 256 + threadIdx.x;
    float acc = 0.f;
#pragma unroll
    for (int c = 0; c < 7; ++c) acc = fmaf(wrow[c], outW[c * DM + k], acc);
    wf[(size_t)j * DM + k] = (_Float16)acc;
  }
  if (threadIdx.x == 0) {
    float bb = dbih0[j];
#pragma unroll
    for (int c = 0; c < 7; ++c) bb = fmaf(wrow[c], outb[c], bb);
    bf0[j] = bb;
  }
}

__global__ __launch_bounds__(512) void gru_persist(
    const float* __restrict__ xe,  const float* __restrict__ xme,
    const float* __restrict__ xd,  const float* __restrict__ xmd,
    const float* __restrict__ eWih0, const float* __restrict__ eWhh0,
    const float* __restrict__ ebih0, const float* __restrict__ ebhh0,
    const float* __restrict__ eWih1, const float* __restrict__ eWhh1,
    const float* __restrict__ ebih1, const float* __restrict__ ebhh1,
    const float* __restrict__ dWih0, const float* __restrict__ dWhh0,
    const float* __restrict__ dbih0, const float* __restrict__ dbhh0,
    const float* __restrict__ dWih1, const float* __restrict__ dWhh1,
    const float* __restrict__ dbih1, const float* __restrict__ dbhh1,
    char* __restrict__ ws) {
  extern __shared__ char smem[];
  const int tid = threadIdx.x, bx = blockIdx.x;
  const int lane = tid & 63;
  const int w = tid >> 6;
  const int bg = w & 3, kslice = w >> 2;
  const int bs = bg << 4, kb0 = kslice << 4;
  const int u0 = bx << 2;
  const int bA = ((w & 3) << 4) + (lane & 15);   // epilogue batch coord
  const int ulA = lane >> 4;                      // epilogue unit coord

  unsigned* leaf = (unsigned*)ws;
  unsigned* root = (unsigned*)(ws + 4096);
  _Float16* h0p[2] = {(_Float16*)(ws + OFF_H0P0), (_Float16*)(ws + OFF_H0P0 + HB)};
  _Float16* eh1[2] = {(_Float16*)(ws + OFF_EH10), (_Float16*)(ws + OFF_EH10 + HB)};
  _Float16* dh1 = (_Float16*)(ws + OFF_DH1);
  const _Float16* wf = (const _Float16*)(ws + OFF_WF);
  const float* bf0 = (const float*)(ws + OFF_BF0);

  half8 y0[16], y1[16];
  f32x4 carryI = ZERO4, carryA = ZERO4, carryB = ZERO4;
  float pxr = 0.f, pxz = 0.f, pxn = 0.f;
  float hA = 0.f, hB = 0.f;
  unsigned ep = 0;

  // ---------- encoder weights -> LDS ----------
  fill_tile_f32(smem, L_TA0, eWhh0, u0, 0, 1, 2, -1, tid);   // gh0: r,z,nh | zeros
  fill_tile_f32(smem, L_TB0, eWih1, u0, 0, 1, -1, 2, tid);   // gi1: r,z | zeros | ni
  fill_tile_f32(smem, L_TB1, eWhh1, u0, 0, 1, 2, -1, tid);   // gh1: r,z,nh | zeros
  fill_small(smem, u0, tid, eWih0, ebih0, ebhh0, ebih1, ebhh1, nullptr);
  __syncthreads();
  if (w < 4) x_pre(smem, 1, xe, xme, 0, TENC, bA, ulA, pxr, pxz, pxn);

  // ---------- encoder: interval t = L0(t) + L1(t-2) ----------
  for (int t = 0; t < TENC; ++t) {
    bar_wait(root, tid, ep);
    yload(y0, h0p[t & 1], kb0, lane, bs);                       // h0(t-1)
    if (t >= 2) yload(y1, eh1[(t - 3) & 1], kb0, lane, bs);     // h1(t-3)
    ysync16(y0);
    f32x4 aA = gemm_reg(smem, L_TA0, kb0, lane, y0, ZERO4);     // gh0·h0(t-1)
    tr_store(smem, L_TRA, w, lane, aA);
    if (t >= 2) {
      f32x4 aB = gemm_reg(smem, L_TB1, kb0, lane, y1, carryI);  // + gi1·h0(t-2)
      tr_store(smem, L_TRB, w, lane, aB);
    }
    __syncthreads();
    if (w < 4) epi(smem, L_TRA, L_HSTA, 0, L_BA, pxr, pxz, pxn, tid, hA);
    else if (t >= 2) epi(smem, L_TRB, L_HSTB, 4, L_BB, 0.f, 0.f, 0.f, tid, hB);
    __syncthreads();
    if (tid < 64) st8(h0p[(t & 1) ^ 1], u0, tid, smem + L_HSTA);
    else if (t >= 2 && tid < 128) st8(eh1[t & 1], u0, tid - 64, smem + L_HSTB);
    bar_arrive(leaf, root, tid, bx, ++ep);
    carryI = gemm_reg(smem, L_TB0, kb0, lane, y0, ZERO4);       // gi1·h0(t-1)
    if (w < 4 && t + 1 < TENC) x_pre(smem, 1, xe, xme, t + 1, TENC, bA, ulA, pxr, pxz, pxn);
  }
  // drain E1: L1(190) -> eh1[0]
  {
    bar_wait(root, tid, ep);
    yload(y0, h0p[0], kb0, lane, bs);                           // h0(191)
    yload(y1, eh1[1], kb0, lane, bs);                           // h1(189)
    ysync16(y0);
    f32x4 aB = gemm_reg(smem, L_TB1, kb0, lane, y1, carryI);
    tr_store(smem, L_TRB, w, lane, aB);
    __syncthreads();
    if (w >= 4) epi(smem, L_TRB, L_HSTB, 4, L_BB, 0.f, 0.f, 0.f, tid, hB);
    __syncthreads();
    if (tid >= 64 && tid < 128) st8(eh1[0], u0, tid - 64, smem + L_HSTB);
    bar_arrive(leaf, root, tid, bx, ++ep);
    carryI = gemm_reg(smem, L_TB0, kb0, lane, y0, ZERO4);       // gi1·h0(191)
  }
  // drain E2: L1(191) -> dh1[0]; then swap to decoder weights
  {
    bar_wait(root, tid, ep);
    yload(y1, eh1[0], kb0, lane, bs);                           // h1(190)
    ysync16(y1);
    f32x4 aB = gemm_reg(smem, L_TB1, kb0, lane, y1, carryI);
    tr_store(smem, L_TRB, w, lane, aB);
    __syncthreads();
    if (w >= 4) epi(smem, L_TRB, L_HSTB, 4, L_BB, 0.f, 0.f, 0.f, tid, hB);
    __syncthreads();
    if (tid >= 64 && tid < 128) st8(dh1, u0, tid - 64, smem + L_HSTB);
    bar_arrive(leaf, root, tid, bx, ++ep);
    // decoder weights -> LDS (read-only globals; our own compute done)
    fill_tile_f32(smem, L_TA0, dWhh0, u0, 0, 1, 2, -1, tid);
    fill_tile_f16(smem, L_TA1, wf,    u0, 0, 1, -1, 2, tid);
    fill_tile_f32(smem, L_TB0, dWih1, u0, 0, 1, -1, 2, tid);
    fill_tile_f32(smem, L_TB1, dWhh1, u0, 0, 1, 2, -1, tid);
    fill_small(smem, u0, tid, dWih0, dbih0, dbhh0, dbih1, dbhh1, bf0);
    __syncthreads();
    if (w < 4) x_pre(smem, 1, xd, xmd, 0, TDEC, bA, ulA, pxr, pxz, pxn);
  }

  // ---------- label: interval d = L0d(d) + L1d(d-2) ----------
  for (int d = 0; d < LBL; ++d) {
    bar_wait(root, tid, ep);
    yload(y0, h0p[d & 1], kb0, lane, bs);                       // h0 step 192+d-1
    if (d >= 2) yload(y1, dh1 + (size_t)(d - 2) * HE, kb0, lane, bs);  // h1d(d-3)
    ysync16(y0);
    f32x4 aA = gemm_reg(smem, L_TA0, kb0, lane, y0, ZERO4);
    tr_store(smem, L_TRA, w, lane, aA);
    if (d >= 2) {
      f32x4 aB = gemm_reg(smem, L_TB1, kb0, lane, y1, carryI);
      tr_store(smem, L_TRB, w, lane, aB);
    }
    __syncthreads();
    if (w < 4) epi(smem, L_TRA, L_HSTA, 0, L_BA, pxr, pxz, pxn, tid, hA);
    else if (d >= 2) epi(smem, L_TRB, L_HSTB, 4, L_BB, 0.f, 0.f, 0.f, tid, hB);
    __syncthreads();
    if (tid < 64) st8(h0p[(d & 1) ^ 1], u0, tid, smem + L_HSTA);
    else if (d >= 2 && tid < 128) st8(dh1 + (size_t)(d - 1) * HE, u0, tid - 64, smem + L_HSTB);
    bar_arrive(leaf, root, tid, bx, ++ep);
    carryI = gemm_reg(smem, L_TB0, kb0, lane, y0, ZERO4);
    if (w < 4 && d + 1 < LBL) x_pre(smem, 1, xd, xmd, d + 1, TDEC, bA, ulA, pxr, pxz, pxn);
  }
  // drain D1: L1d(46) -> dh1[47]; seed carryI(gi1·h0d(47)) + carryA(gh0·h0d(47))
  {
    bar_wait(root, tid, ep);
    yload(y0, h0p[0], kb0, lane, bs);                           // h0d(47)
    yload(y1, dh1 + (size_t)46 * HE, kb0, lane, bs);            // h1d(45)
    ysync16(y0);
    f32x4 aB = gemm_reg(smem, L_TB1, kb0, lane, y1, carryI);
    tr_store(smem, L_TRB, w, lane, aB);
    __syncthreads();
    if (w >= 4) epi(smem, L_TRB, L_HSTB, 4, L_BB, 0.f, 0.f, 0.f, tid, hB);
    __syncthreads();
    if (tid >= 64 && tid < 128) st8(dh1 + (size_t)47 * HE, u0, tid - 64, smem + L_HSTB);
    bar_arrive(leaf, root, tid, bx, ++ep);
    carryI = gemm_reg(smem, L_TB0, kb0, lane, y0, ZERO4);
    carryA = gemm_reg(smem, L_TA0, kb0, lane, y0, ZERO4);
  }
  // drain D2: L1d(47) -> dh1[48]
  {
    bar_wait(root, tid, ep);
    yload(y1, dh1 + (size_t)47 * HE, kb0, lane, bs);
    ysync16(y1);
    f32x4 aB = gemm_reg(smem, L_TB1, kb0, lane, y1, carryI);
    tr_store(smem, L_TRB, w, lane, aB);
    __syncthreads();
    if (w >= 4) epi(smem, L_TRB, L_HSTB, 4, L_BB, 0.f, 0.f, 0.f, tid, hB);
    __syncthreads();
    if (tid >= 64 && tid < 128) st8(dh1 + (size_t)48 * HE, u0, tid - 64, smem + L_HSTB);
    bar_arrive(leaf, root, tid, bx, ++ep);
    if (w < 4) x_pre(smem, 2, nullptr, xmd, LBL, TDEC, bA, ulA, pxr, pxz, pxn);
  }

  // ---------- autoregressive region: s = 48..215, A/B intervals ----------
  for (int s = LBL; s < TDEC; ++s) {
    // A(s): h0(s) = f(carryA + Wf·h1(s-1) + marks); post: carryB = gh1·h1(s-1)
    bar_wait(root, tid, ep);
    yload(y1, dh1 + (size_t)s * HE, kb0, lane, bs);
    ysync16(y1);
    f32x4 aA = gemm_reg(smem, L_TA1, kb0, lane, y1, carryA);
    tr_store(smem, L_TRA, w, lane, aA);
    __syncthreads();
    if (w < 4) epi(smem, L_TRA, L_HSTA, 0, L_BAA, pxr, pxz, pxn, tid, hA);
    __syncthreads();
    if (tid < 64) st8(h0p[(s & 1) ^ 1], u0, tid, smem + L_HSTA);
    bar_arrive(leaf, root, tid, bx, ++ep);
    carryB = gemm_reg(smem, L_TB1, kb0, lane, y1, ZERO4);
    // B(s): h1(s) = f(carryB + gi1·h0(s)); post: carryA = gh0·h0(s), x_pre(s+1)
    bar_wait(root, tid, ep);
    yload(y0, h0p[(s & 1) ^ 1], kb0, lane, bs);
    ysync16(y0);
    f32x4 aB = gemm_reg(smem, L_TB0, kb0, lane, y0, carryB);
    tr_store(smem, L_TRB, w, lane, aB);
    __syncthreads();
    if (w >= 4) epi(smem, L_TRB, L_HSTB, 4, L_BB, 0.f, 0.f, 0.f, tid, hB);
    __syncthreads();
    if (tid >= 64 && tid < 128) st8(dh1 + (size_t)(s + 1) * HE, u0, tid - 64, smem + L_HSTB);
    bar_arrive(leaf, root, tid, bx, ++ep);
    carryA = gemm_reg(smem, L_TA0, kb0, lane, y0, ZERO4);
    if (w < 4 && s + 1 < TDEC) x_pre(smem, 2, nullptr, xmd, s + 1, TDEC, bA, ulA, pxr, pxz, pxn);
  }
}

// ---- epilogue projection: preds from stored h1 history (packed f16)
__global__ __launch_bounds__(64) void proj_kernel(const char* __restrict__ ws,
                                                  const float* __restrict__ outW,
                                                  const float* __restrict__ outb,
                                                  float* __restrict__ out) {
  const int ti = blockIdx.x / 7, c = blockIdx.x % 7;
  const _Float16* h = (const _Float16*)(ws + OFF_DH1) + (size_t)(LBL + 1 + ti) * HE;
  const int b = threadIdx.x;
  const float* wrow = outW + c * DM;
  float acc = outb[c];
#pragma unroll 4
  for (int k8 = 0; k8 < 128; ++k8) {
    const half8 hv = *(const half8*)(h + ((size_t)k8 * 64 + b) * 8);
    const float* wp = wrow + k8 * 8;
#pragma unroll
    for (int j = 0; j < 8; ++j) acc = fmaf((float)hv[j], wp[j], acc);
  }
  out[(size_t)b * (NPRED * 7) + ti * 7 + c] = acc;
}

extern "C" void kernel_launch(void* const* d_in, const int* in_sizes, int n_in,
                              void* d_out, int out_size, void* d_ws, size_t ws_size,
                              hipStream_t stream) {
  (void)in_sizes; (void)n_in; (void)out_size; (void)ws_size;
  const float* xe    = (const float*)d_in[0];
  const float* xme   = (const float*)d_in[1];
  const float* xd    = (const float*)d_in[2];
  const float* xmd   = (const float*)d_in[3];
  const float* eWih0 = (const float*)d_in[4];
  const float* eWhh0 = (const float*)d_in[5];
  const float* ebih0 = (const float*)d_in[6];
  const float* ebhh0 = (const float*)d_in[7];
  const float* eWih1 = (const float*)d_in[8];
  const float* eWhh1 = (const float*)d_in[9];
  const float* ebih1 = (const float*)d_in[10];
  const float* ebhh1 = (const float*)d_in[11];
  const float* dWih0 = (const float*)d_in[12];
  const float* dWhh0 = (const float*)d_in[13];
  const float* dbih0 = (const float*)d_in[14];
  const float* dbhh0 = (const float*)d_in[15];
  const float* dWih1 = (const float*)d_in[16];
  const float* dWhh1 = (const float*)d_in[17];
  const float* dbih1 = (const float*)d_in[18];
  const float* dbhh1 = (const float*)d_in[19];
  const float* outW  = (const float*)d_in[20];
  const float* outb  = (const float*)d_in[21];
  char* ws = (char*)d_ws;

  hipFuncSetAttribute(reinterpret_cast<const void*>(gru_persist),
                      hipFuncAttributeMaxDynamicSharedMemorySize, SMEM_BYTES);

  // zero: barrier counters + h0pack slot0 + encoder h1pack BOTH slots
  hipMemsetAsync(ws, 0, OFF_H0P0 + HB, stream);
  hipMemsetAsync(ws + OFF_EH10, 0, 2 * HB, stream);

  prep_wf<<<3072, 256, 0, stream>>>(dWih0, dbih0, outW, outb, ws);
  gru_persist<<<256, 512, SMEM_BYTES, stream>>>(xe, xme, xd, xmd,
                                                eWih0, eWhh0, ebih0, ebhh0,
                                                eWih1, eWhh1, ebih1, ebhh1,
                                                dWih0, dWhh0, dbih0, dbhh0,
                                                dWih1, dWhh1, dbih1, dbhh1, ws);
  proj_kernel<<<NPRED * 7, 64, 0, stream>>>(ws, outW, outb, (float*)d_out);
}